// Round 1
// baseline (613.275 us; speedup 1.0000x reference)
//
#include <hip/hip_runtime.h>
#include <hip/hip_bf16.h>

// Problem constants
#define B_ 16
#define N_ 512
#define H_ 8
#define D_ 128
#define HD_ 1024
#define SCALE_ 0.08838834764831845f  // 1/sqrt(128)

// ---------------------------------------------------------------------------
// Kernel 1: fused QKV projection.
// C(8192 x 3072) = x(8192 x 128) @ [Wq|Wk|Wv](128 x 3072), + bias, * mask
// (q additionally * scale). q,v stored (B,H,N,D); k stored transposed
// (B,H,D,N) via LDS transpose so the attention kernel reads kT coalesced.
// Tiling: 64x64 per block, K-chunks of 32, 256 threads, 4x4 per thread.
// ---------------------------------------------------------------------------
__global__ __launch_bounds__(256) void qkv_kernel(
    const float* __restrict__ x, const float* __restrict__ mask,
    const float* __restrict__ Wq, const float* __restrict__ bq,
    const float* __restrict__ Wk, const float* __restrict__ bk,
    const float* __restrict__ Wv, const float* __restrict__ bv,
    float* __restrict__ q, float* __restrict__ kT, float* __restrict__ v)
{
    const int cb = blockIdx.x % 48;   // col tile (64 wide) in [0,3072)
    const int by = blockIdx.x / 48;   // row tile (64 tall) in [0,8192)
    const int row0 = by * 64;
    const int c0 = cb * 64;
    const int which = c0 >> 10;       // 0=q, 1=k, 2=v
    const int w0 = c0 & 1023;         // col offset within the 1024-wide W

    const float* W  = (which == 0) ? Wq : (which == 1) ? Wk : Wv;
    const float* bi = (which == 0) ? bq : (which == 1) ? bk : bv;

    __shared__ alignas(16) float As[32][65];  // As[k][row]
    __shared__ alignas(16) float Bs[32][64];  // Bs[k][col]
    __shared__ alignas(16) float Tr[64][65];  // k-transpose staging

    const int t = threadIdx.x;
    const int tx = t & 15;            // cols tx*4 .. tx*4+3
    const int ty = t >> 4;            // rows ty*4 .. ty*4+3

    float acc[4][4] = {};

    for (int k0 = 0; k0 < 128; k0 += 32) {
        #pragma unroll
        for (int qq = 0; qq < 8; qq++) {
            int lin = t + 256 * qq;
            int ar = lin >> 5, ak = lin & 31;
            As[ak][ar] = x[(row0 + ar) * 128 + k0 + ak];
        }
        #pragma unroll
        for (int qq = 0; qq < 8; qq++) {
            int lin = t + 256 * qq;
            int br = lin >> 6, bc = lin & 63;
            Bs[br][bc] = W[(k0 + br) * 1024 + w0 + bc];
        }
        __syncthreads();
        #pragma unroll
        for (int kk = 0; kk < 32; kk++) {
            float a0 = As[kk][ty * 4 + 0];
            float a1 = As[kk][ty * 4 + 1];
            float a2 = As[kk][ty * 4 + 2];
            float a3 = As[kk][ty * 4 + 3];
            float4 bv4 = *(const float4*)&Bs[kk][tx * 4];
            acc[0][0] += a0 * bv4.x; acc[0][1] += a0 * bv4.y; acc[0][2] += a0 * bv4.z; acc[0][3] += a0 * bv4.w;
            acc[1][0] += a1 * bv4.x; acc[1][1] += a1 * bv4.y; acc[1][2] += a1 * bv4.z; acc[1][3] += a1 * bv4.w;
            acc[2][0] += a2 * bv4.x; acc[2][1] += a2 * bv4.y; acc[2][2] += a2 * bv4.z; acc[2][3] += a2 * bv4.w;
            acc[3][0] += a3 * bv4.x; acc[3][1] += a3 * bv4.y; acc[3][2] += a3 * bv4.z; acc[3][3] += a3 * bv4.w;
        }
        __syncthreads();
    }

    const int b = row0 >> 9;
    const int h = w0 >> 7;
    const int d0 = w0 & 127;          // 0 or 64

    if (which == 1) {
        // k: stage transposed tile in LDS, then write kT coalesced along i
        #pragma unroll
        for (int rr = 0; rr < 4; rr++) {
            int row = row0 + ty * 4 + rr;
            float m = mask[row];
            #pragma unroll
            for (int cc = 0; cc < 4; cc++) {
                int cl = tx * 4 + cc;
                Tr[cl][ty * 4 + rr] = (acc[rr][cc] + bi[w0 + cl]) * m;
            }
        }
        __syncthreads();
        const int i0 = row0 & 511;
        float* kbase = kT + ((size_t)(b * 8 + h) * 128) * 512;
        #pragma unroll
        for (int qq = 0; qq < 16; qq++) {
            int lin = t + 256 * qq;
            int dl = lin >> 6, il = lin & 63;
            kbase[(d0 + dl) * 512 + i0 + il] = Tr[dl][il];
        }
    } else {
        float* dst = (which == 0) ? q : v;
        const float sc = (which == 0) ? SCALE_ : 1.0f;
        #pragma unroll
        for (int rr = 0; rr < 4; rr++) {
            int row = row0 + ty * 4 + rr;
            int i = row & 511;
            float m = mask[row] * sc;
            float4 o;
            o.x = (acc[rr][0] + bi[w0 + tx * 4 + 0]) * m;
            o.y = (acc[rr][1] + bi[w0 + tx * 4 + 1]) * m;
            o.z = (acc[rr][2] + bi[w0 + tx * 4 + 2]) * m;
            o.w = (acc[rr][3] + bi[w0 + tx * 4 + 3]) * m;
            *(float4*)&dst[((size_t)(b * 8 + h) * 512 + i) * 128 + d0 + tx * 4] = o;
        }
    }
}

// ---------------------------------------------------------------------------
// Kernel 2: attention. One block = one (b,h) and 16 query rows.
// Full 512-wide score rows in LDS (no online softmax needed).
// S = q@kT + dist, amask==0 -> -1e9 -> exp 0; normalization folded into PV.
// ---------------------------------------------------------------------------
__global__ __launch_bounds__(256) void attn_kernel(
    const float* __restrict__ q, const float* __restrict__ kT,
    const float* __restrict__ v, const float* __restrict__ dist,
    const float* __restrict__ mask, float* __restrict__ y)
{
    const int bh = blockIdx.x >> 5;     // 0..127
    const int itile = blockIdx.x & 31;  // 0..31
    const int b = bh >> 3, h = bh & 7;
    const int i0 = itile * 16;

    const float* qb = q + (size_t)bh * 512 * 128;
    const float* kb = kT + (size_t)bh * 128 * 512;
    const float* vb = v + (size_t)bh * 512 * 128;

    __shared__ alignas(16) float qs[16][128];
    __shared__ float Sld[16][516];
    __shared__ float msk[16];
    __shared__ float rsld[16];

    const int t = threadIdx.x;

    #pragma unroll
    for (int qq = 0; qq < 8; qq++) {
        int lin = t + 256 * qq;
        qs[lin >> 7][lin & 127] = qb[(i0 + (lin >> 7)) * 128 + (lin & 127)];
    }
    if (t < 16) msk[t] = mask[b * 512 + i0 + t];
    __syncthreads();

    // Phase 1: S[r][j] for j = t and j = 256+t
    float s0[16] = {};
    float s1[16] = {};
    for (int d = 0; d < 128; d += 4) {
        float k0a = kb[(d + 0) * 512 + t];
        float k0b = kb[(d + 1) * 512 + t];
        float k0c = kb[(d + 2) * 512 + t];
        float k0d = kb[(d + 3) * 512 + t];
        float k1a = kb[(d + 0) * 512 + 256 + t];
        float k1b = kb[(d + 1) * 512 + 256 + t];
        float k1c = kb[(d + 2) * 512 + 256 + t];
        float k1d = kb[(d + 3) * 512 + 256 + t];
        #pragma unroll
        for (int r = 0; r < 16; r++) {
            float4 qv = *(const float4*)&qs[r][d];
            s0[r] += qv.x * k0a + qv.y * k0b + qv.z * k0c + qv.w * k0d;
            s1[r] += qv.x * k1a + qv.y * k1b + qv.z * k1c + qv.w * k1d;
        }
    }

    const float mj0 = mask[b * 512 + t];
    const float mj1 = mask[b * 512 + 256 + t];
    #pragma unroll
    for (int r = 0; r < 16; r++) {
        float mi = msk[r];
        float dv0 = dist[(b * 512 + i0 + r) * 512 + t];
        float dv1 = dist[(b * 512 + i0 + r) * 512 + 256 + t];
        Sld[r][t]       = (mi * mj0 == 0.0f) ? -1e9f : s0[r] + dv0;
        Sld[r][256 + t] = (mi * mj1 == 0.0f) ? -1e9f : s1[r] + dv1;
    }
    __syncthreads();

    // Softmax: wave w handles rows w*4 .. w*4+3
    const int wv = t >> 6;
    const int ln = t & 63;
    for (int rr = 0; rr < 4; rr++) {
        int r = wv * 4 + rr;
        float p[8];
        float m = -3e38f;
        #pragma unroll
        for (int jj = 0; jj < 8; jj++) {
            float sv = Sld[r][ln + 64 * jj];
            p[jj] = sv;
            m = fmaxf(m, sv);
        }
        #pragma unroll
        for (int off = 32; off; off >>= 1) m = fmaxf(m, __shfl_xor(m, off));
        float sum = 0.0f;
        #pragma unroll
        for (int jj = 0; jj < 8; jj++) {
            float pv = (p[jj] <= -1e8f) ? 0.0f : __expf(p[jj] - m);
            p[jj] = pv;
            sum += pv;
        }
        #pragma unroll
        for (int off = 32; off; off >>= 1) sum += __shfl_xor(sum, off);
        #pragma unroll
        for (int jj = 0; jj < 8; jj++) Sld[r][ln + 64 * jj] = p[jj];
        if (ln == 0) rsld[r] = (sum > 0.0f) ? 1.0f / sum : 0.0f;
    }
    __syncthreads();

    // Phase 2: Y[r][d] = sum_j P[r][j] * v[j][d]; thread owns 2 rows x 4 d's
    const int d4 = (t & 31) * 4;
    const int rg = t >> 5;   // 0..7 -> rows rg*2, rg*2+1
    float4 a0 = {0, 0, 0, 0}, a1 = {0, 0, 0, 0};
    #pragma unroll 4
    for (int j = 0; j < 512; j++) {
        float4 vv = *(const float4*)&vb[j * 128 + d4];
        float p0 = Sld[rg * 2 + 0][j];
        float p1 = Sld[rg * 2 + 1][j];
        a0.x += p0 * vv.x; a0.y += p0 * vv.y; a0.z += p0 * vv.z; a0.w += p0 * vv.w;
        a1.x += p1 * vv.x; a1.y += p1 * vv.y; a1.z += p1 * vv.z; a1.w += p1 * vv.w;
    }
    const float r0s = rsld[rg * 2 + 0];
    const float r1s = rsld[rg * 2 + 1];
    a0.x *= r0s; a0.y *= r0s; a0.z *= r0s; a0.w *= r0s;
    a1.x *= r1s; a1.y *= r1s; a1.z *= r1s; a1.w *= r1s;
    const int i_a = i0 + rg * 2;
    *(float4*)&y[((size_t)(b * 512 + i_a + 0)) * 1024 + h * 128 + d4] = a0;
    *(float4*)&y[((size_t)(b * 512 + i_a + 1)) * 1024 + h * 128 + d4] = a1;
}

// ---------------------------------------------------------------------------
// Kernel 3: output projection. out(8192 x 128) = Y(8192 x 1024) @ Wo + bo,
// then * mask[row]. 32x128 tile per block, K-chunks of 32.
// ---------------------------------------------------------------------------
__global__ __launch_bounds__(256) void oproj_kernel(
    const float* __restrict__ Y, const float* __restrict__ Wo,
    const float* __restrict__ bo, const float* __restrict__ mask,
    float* __restrict__ out)
{
    const int row0 = blockIdx.x * 32;
    __shared__ alignas(16) float As[32][33];   // As[k][row]
    __shared__ alignas(16) float Bs[32][128];  // Bs[k][col]

    const int t = threadIdx.x;
    const int tx = t & 31;   // cols tx*4 .. tx*4+3
    const int ty = t >> 5;   // rows ty*4 .. ty*4+3

    float acc[4][4] = {};

    for (int k0 = 0; k0 < 1024; k0 += 32) {
        #pragma unroll
        for (int qq = 0; qq < 4; qq++) {
            int lin = t + 256 * qq;
            int ar = lin >> 5, ak = lin & 31;
            As[ak][ar] = Y[(size_t)(row0 + ar) * 1024 + k0 + ak];
        }
        #pragma unroll
        for (int qq = 0; qq < 16; qq++) {
            int lin = t + 256 * qq;
            int br = lin >> 7, bc = lin & 127;
            Bs[br][bc] = Wo[(k0 + br) * 128 + bc];
        }
        __syncthreads();
        #pragma unroll
        for (int kk = 0; kk < 32; kk++) {
            float a0 = As[kk][ty * 4 + 0];
            float a1 = As[kk][ty * 4 + 1];
            float a2 = As[kk][ty * 4 + 2];
            float a3 = As[kk][ty * 4 + 3];
            float4 bv4 = *(const float4*)&Bs[kk][tx * 4];
            acc[0][0] += a0 * bv4.x; acc[0][1] += a0 * bv4.y; acc[0][2] += a0 * bv4.z; acc[0][3] += a0 * bv4.w;
            acc[1][0] += a1 * bv4.x; acc[1][1] += a1 * bv4.y; acc[1][2] += a1 * bv4.z; acc[1][3] += a1 * bv4.w;
            acc[2][0] += a2 * bv4.x; acc[2][1] += a2 * bv4.y; acc[2][2] += a2 * bv4.z; acc[2][3] += a2 * bv4.w;
            acc[3][0] += a3 * bv4.x; acc[3][1] += a3 * bv4.y; acc[3][2] += a3 * bv4.z; acc[3][3] += a3 * bv4.w;
        }
        __syncthreads();
    }

    #pragma unroll
    for (int rr = 0; rr < 4; rr++) {
        int row = row0 + ty * 4 + rr;
        float m = mask[row];
        float4 o;
        o.x = (acc[rr][0] + bo[tx * 4 + 0]) * m;
        o.y = (acc[rr][1] + bo[tx * 4 + 1]) * m;
        o.z = (acc[rr][2] + bo[tx * 4 + 2]) * m;
        o.w = (acc[rr][3] + bo[tx * 4 + 3]) * m;
        *(float4*)&out[(size_t)row * 128 + tx * 4] = o;
    }
}

extern "C" void kernel_launch(void* const* d_in, const int* in_sizes, int n_in,
                              void* d_out, int out_size, void* d_ws, size_t ws_size,
                              hipStream_t stream) {
    const float* x    = (const float*)d_in[0];
    const float* dist = (const float*)d_in[1];
    const float* mask = (const float*)d_in[2];
    const float* Wq   = (const float*)d_in[3];
    const float* bq   = (const float*)d_in[4];
    const float* Wk   = (const float*)d_in[5];
    const float* bk   = (const float*)d_in[6];
    const float* Wv   = (const float*)d_in[7];
    const float* bv   = (const float*)d_in[8];
    const float* Wo   = (const float*)d_in[9];
    const float* bo   = (const float*)d_in[10];
    float* out = (float*)d_out;

    const size_t per = (size_t)B_ * H_ * N_ * D_;  // 8,388,608 floats
    float* qb = (float*)d_ws;
    float* kb = qb + per;   // transposed (B,H,D,N)
    float* vb = kb + per;
    float* yb = vb + per;   // (B,N,H*D)

    qkv_kernel<<<6144, 256, 0, stream>>>(x, mask, Wq, bq, Wk, bk, Wv, bv, qb, kb, vb);
    attn_kernel<<<4096, 256, 0, stream>>>(qb, kb, vb, dist, mask, yb);
    oproj_kernel<<<256, 256, 0, stream>>>(yb, Wo, bo, mask, out);
}

// Round 2
// 407.947 us; speedup vs baseline: 1.5033x; 1.5033x over previous
//
#include <hip/hip_runtime.h>
#include <hip/hip_bf16.h>

// Problem constants
#define B_ 16
#define N_ 512
#define H_ 8
#define D_ 128
#define HD_ 1024
#define SCALE_ 0.08838834764831845f  // 1/sqrt(128)

typedef __attribute__((ext_vector_type(8))) short bf16x8;  // 8 bf16 = 4 VGPR
typedef __attribute__((ext_vector_type(4))) float f32x4;   // MFMA 16x16 C/D

__device__ __forceinline__ unsigned short f2bf(float f) {
    union { __hip_bfloat16 h; unsigned short u; } cv;
    cv.h = __float2bfloat16(f);
    return cv.u;
}

// ---------------------------------------------------------------------------
// Kernel 1: fused QKV projection (fp32 math, bf16 outputs).
// q: (B,H,N,D) bf16, *mask*scale.  k: (B,H,N,D) bf16, *mask.
// v: (B,H,D,N) bf16 TRANSPOSED (for PV B-fragment contiguity), *mask.
// ---------------------------------------------------------------------------
__global__ __launch_bounds__(256) void qkv_kernel(
    const float* __restrict__ x, const float* __restrict__ mask,
    const float* __restrict__ Wq, const float* __restrict__ bq,
    const float* __restrict__ Wk, const float* __restrict__ bk,
    const float* __restrict__ Wv, const float* __restrict__ bv,
    unsigned short* __restrict__ q, unsigned short* __restrict__ k,
    unsigned short* __restrict__ vT)
{
    const int cb = blockIdx.x % 48;
    const int by = blockIdx.x / 48;
    const int row0 = by * 64;
    const int c0 = cb * 64;
    const int which = c0 >> 10;       // 0=q, 1=k, 2=v
    const int w0 = c0 & 1023;

    const float* W  = (which == 0) ? Wq : (which == 1) ? Wk : Wv;
    const float* bi = (which == 0) ? bq : (which == 1) ? bk : bv;

    __shared__ alignas(16) float As[32][65];
    __shared__ alignas(16) float Bs[32][64];
    __shared__ alignas(16) float Tr[64][65];

    const int t = threadIdx.x;
    const int tx = t & 15;
    const int ty = t >> 4;

    float acc[4][4] = {};

    for (int k0 = 0; k0 < 128; k0 += 32) {
        #pragma unroll
        for (int qq = 0; qq < 8; qq++) {
            int lin = t + 256 * qq;
            int ar = lin >> 5, ak = lin & 31;
            As[ak][ar] = x[(row0 + ar) * 128 + k0 + ak];
        }
        #pragma unroll
        for (int qq = 0; qq < 8; qq++) {
            int lin = t + 256 * qq;
            int br = lin >> 6, bc = lin & 63;
            Bs[br][bc] = W[(k0 + br) * 1024 + w0 + bc];
        }
        __syncthreads();
        #pragma unroll
        for (int kk = 0; kk < 32; kk++) {
            float a0 = As[kk][ty * 4 + 0];
            float a1 = As[kk][ty * 4 + 1];
            float a2 = As[kk][ty * 4 + 2];
            float a3 = As[kk][ty * 4 + 3];
            float4 bv4 = *(const float4*)&Bs[kk][tx * 4];
            acc[0][0] += a0 * bv4.x; acc[0][1] += a0 * bv4.y; acc[0][2] += a0 * bv4.z; acc[0][3] += a0 * bv4.w;
            acc[1][0] += a1 * bv4.x; acc[1][1] += a1 * bv4.y; acc[1][2] += a1 * bv4.z; acc[1][3] += a1 * bv4.w;
            acc[2][0] += a2 * bv4.x; acc[2][1] += a2 * bv4.y; acc[2][2] += a2 * bv4.z; acc[2][3] += a2 * bv4.w;
            acc[3][0] += a3 * bv4.x; acc[3][1] += a3 * bv4.y; acc[3][2] += a3 * bv4.z; acc[3][3] += a3 * bv4.w;
        }
        __syncthreads();
    }

    const int b = row0 >> 9;
    const int h = w0 >> 7;
    const int d0 = w0 & 127;

    if (which == 2) {
        // v: stage transposed tile in LDS, write vT (B,H,D,N) bf16
        #pragma unroll
        for (int rr = 0; rr < 4; rr++) {
            int row = row0 + ty * 4 + rr;
            float m = mask[row];
            #pragma unroll
            for (int cc = 0; cc < 4; cc++) {
                int cl = tx * 4 + cc;
                Tr[cl][ty * 4 + rr] = (acc[rr][cc] + bi[w0 + cl]) * m;
            }
        }
        __syncthreads();
        const int i0 = row0 & 511;
        unsigned short* vbase = vT + (size_t)(b * 8 + h) * 128 * 512;
        #pragma unroll
        for (int qq = 0; qq < 16; qq++) {
            int lin = t + 256 * qq;
            int dl = lin >> 6, il = lin & 63;
            vbase[(size_t)(d0 + dl) * 512 + i0 + il] = f2bf(Tr[dl][il]);
        }
    } else {
        unsigned short* dst = (which == 0) ? q : k;
        const float sc = (which == 0) ? SCALE_ : 1.0f;
        #pragma unroll
        for (int rr = 0; rr < 4; rr++) {
            int row = row0 + ty * 4 + rr;
            int i = row & 511;
            float m = mask[row] * sc;
            short4 o;
            o.x = (short)f2bf((acc[rr][0] + bi[w0 + tx * 4 + 0]) * m);
            o.y = (short)f2bf((acc[rr][1] + bi[w0 + tx * 4 + 1]) * m);
            o.z = (short)f2bf((acc[rr][2] + bi[w0 + tx * 4 + 2]) * m);
            o.w = (short)f2bf((acc[rr][3] + bi[w0 + tx * 4 + 3]) * m);
            *(short4*)&dst[((size_t)(b * 8 + h) * 512 + i) * 128 + d0 + tx * 4] = o;
        }
    }
}

// ---------------------------------------------------------------------------
// Kernel 2: attention via bf16 MFMA. One block = (b,h, 16 query rows).
// S = QK^T by mfma_16x16x32 (A=Q natural, B=K natural) -> LDS fp32 with
// dist+amask fused; wave softmax; P bf16 in LDS; Y = PV by mfma (A=P from
// LDS, B=vT global); 1/sum folded into epilogue.
// MFMA fragment layouts (verified m89/m91): A[m=lane&15][k=(lane>>4)*8+j],
// B[k=(lane>>4)*8+j][n=lane&15], C/D col=lane&15 row=(lane>>4)*4+reg.
// ---------------------------------------------------------------------------
__global__ __launch_bounds__(256) void attn_kernel(
    const unsigned short* __restrict__ q, const unsigned short* __restrict__ k,
    const unsigned short* __restrict__ vT, const float* __restrict__ dist,
    const float* __restrict__ mask, float* __restrict__ y)
{
    const int bh = blockIdx.x >> 5;
    const int itile = blockIdx.x & 31;
    const int b = bh >> 3, h = bh & 7;
    const int i0 = itile * 16;

    const unsigned short* qb = q + (size_t)bh * 512 * 128;
    const unsigned short* kb = k + (size_t)bh * 512 * 128;
    const unsigned short* vb = vT + (size_t)bh * 128 * 512;

    __shared__ float Sld[16][520];
    __shared__ unsigned short Pld[16][528];
    __shared__ float maskb[512];
    __shared__ float msk[16];
    __shared__ float rsld[16];

    const int t = threadIdx.x;
    const int wave = t >> 6;
    const int lane = t & 63;
    const int m16 = lane & 15;   // A-m / B-n / C-col index
    const int g4 = lane >> 4;    // k-group (A/B), row-group (C/D)

    maskb[t] = mask[b * 512 + t];
    maskb[256 + t] = mask[b * 512 + 256 + t];
    if (t < 16) msk[t] = mask[b * 512 + i0 + t];

    // Q A-fragments for this block's 16 rows (reused across all j-tiles)
    bf16x8 aq[4];
    #pragma unroll
    for (int c = 0; c < 4; c++)
        aq[c] = *(const bf16x8*)(qb + (size_t)(i0 + m16) * 128 + c * 32 + g4 * 8);

    __syncthreads();

    // Phase 1: S = QK^T (+dist, amask) -> Sld. Wave w does j-tiles w,w+4,...
    for (int jt = 0; jt < 8; jt++) {
        const int j0 = (wave + 4 * jt) * 16;
        f32x4 acc = {0.f, 0.f, 0.f, 0.f};
        #pragma unroll
        for (int c = 0; c < 4; c++) {
            bf16x8 bk = *(const bf16x8*)(kb + (size_t)(j0 + m16) * 128 + c * 32 + g4 * 8);
            acc = __builtin_amdgcn_mfma_f32_16x16x32_bf16(aq[c], bk, acc, 0, 0, 0);
        }
        const float mj = maskb[j0 + m16];
        #pragma unroll
        for (int r = 0; r < 4; r++) {
            int row = g4 * 4 + r;
            float mi = msk[row];
            float dv = dist[((size_t)b * 512 + i0 + row) * 512 + j0 + m16];
            Sld[row][j0 + m16] = (mi * mj == 0.0f) ? -1e9f : acc[r] + dv;
        }
    }
    __syncthreads();

    // Softmax: wave w owns rows w*4..w*4+3 (full 512-wide rows)
    for (int rr = 0; rr < 4; rr++) {
        int r = wave * 4 + rr;
        float p[8];
        float mx = -3e38f;
        #pragma unroll
        for (int jj = 0; jj < 8; jj++) {
            float sv = Sld[r][lane + 64 * jj];
            p[jj] = sv;
            mx = fmaxf(mx, sv);
        }
        #pragma unroll
        for (int off = 32; off; off >>= 1) mx = fmaxf(mx, __shfl_xor(mx, off));
        float sum = 0.0f;
        #pragma unroll
        for (int jj = 0; jj < 8; jj++) {
            float pv = (p[jj] <= -1e8f) ? 0.0f : __expf(p[jj] - mx);
            p[jj] = pv;
            sum += pv;
        }
        #pragma unroll
        for (int off = 32; off; off >>= 1) sum += __shfl_xor(sum, off);
        #pragma unroll
        for (int jj = 0; jj < 8; jj++) Pld[r][lane + 64 * jj] = f2bf(p[jj]);
        if (lane == 0) rsld[r] = (sum > 0.0f) ? 1.0f / sum : 0.0f;
    }
    __syncthreads();

    // Phase 2: Y = P@V. Wave w owns d columns w*32..w*32+31 (two 16-n tiles).
    const int d0 = wave * 32;
    f32x4 acc0 = {0.f, 0.f, 0.f, 0.f};
    f32x4 acc1 = {0.f, 0.f, 0.f, 0.f};
    for (int jc = 0; jc < 16; jc++) {
        const int j0 = jc * 32;
        bf16x8 ap = *(const bf16x8*)&Pld[m16][j0 + g4 * 8];
        bf16x8 bv0 = *(const bf16x8*)(vb + (size_t)(d0 + m16) * 512 + j0 + g4 * 8);
        bf16x8 bv1 = *(const bf16x8*)(vb + (size_t)(d0 + 16 + m16) * 512 + j0 + g4 * 8);
        acc0 = __builtin_amdgcn_mfma_f32_16x16x32_bf16(ap, bv0, acc0, 0, 0, 0);
        acc1 = __builtin_amdgcn_mfma_f32_16x16x32_bf16(ap, bv1, acc1, 0, 0, 0);
    }
    #pragma unroll
    for (int r = 0; r < 4; r++) {
        int row = g4 * 4 + r;
        float rsv = rsld[row];
        size_t base = ((size_t)(b * 512) + i0 + row) * 1024 + h * 128;
        y[base + d0 + m16] = acc0[r] * rsv;
        y[base + d0 + 16 + m16] = acc1[r] * rsv;
    }
}

// ---------------------------------------------------------------------------
// Kernel 3: output projection (fp32). out = Y @ Wo + bo, * mask[row].
// ---------------------------------------------------------------------------
__global__ __launch_bounds__(256) void oproj_kernel(
    const float* __restrict__ Y, const float* __restrict__ Wo,
    const float* __restrict__ bo, const float* __restrict__ mask,
    float* __restrict__ out)
{
    const int row0 = blockIdx.x * 32;
    __shared__ alignas(16) float As[32][33];
    __shared__ alignas(16) float Bs[32][128];

    const int t = threadIdx.x;
    const int tx = t & 31;
    const int ty = t >> 5;

    float acc[4][4] = {};

    for (int k0 = 0; k0 < 1024; k0 += 32) {
        #pragma unroll
        for (int qq = 0; qq < 4; qq++) {
            int lin = t + 256 * qq;
            int ar = lin >> 5, ak = lin & 31;
            As[ak][ar] = Y[(size_t)(row0 + ar) * 1024 + k0 + ak];
        }
        #pragma unroll
        for (int qq = 0; qq < 16; qq++) {
            int lin = t + 256 * qq;
            int br = lin >> 7, bc = lin & 127;
            Bs[br][bc] = Wo[(k0 + br) * 128 + bc];
        }
        __syncthreads();
        #pragma unroll
        for (int kk = 0; kk < 32; kk++) {
            float a0 = As[kk][ty * 4 + 0];
            float a1 = As[kk][ty * 4 + 1];
            float a2 = As[kk][ty * 4 + 2];
            float a3 = As[kk][ty * 4 + 3];
            float4 bv4 = *(const float4*)&Bs[kk][tx * 4];
            acc[0][0] += a0 * bv4.x; acc[0][1] += a0 * bv4.y; acc[0][2] += a0 * bv4.z; acc[0][3] += a0 * bv4.w;
            acc[1][0] += a1 * bv4.x; acc[1][1] += a1 * bv4.y; acc[1][2] += a1 * bv4.z; acc[1][3] += a1 * bv4.w;
            acc[2][0] += a2 * bv4.x; acc[2][1] += a2 * bv4.y; acc[2][2] += a2 * bv4.z; acc[2][3] += a2 * bv4.w;
            acc[3][0] += a3 * bv4.x; acc[3][1] += a3 * bv4.y; acc[3][2] += a3 * bv4.z; acc[3][3] += a3 * bv4.w;
        }
        __syncthreads();
    }

    #pragma unroll
    for (int rr = 0; rr < 4; rr++) {
        int row = row0 + ty * 4 + rr;
        float m = mask[row];
        float4 o;
        o.x = (acc[rr][0] + bo[tx * 4 + 0]) * m;
        o.y = (acc[rr][1] + bo[tx * 4 + 1]) * m;
        o.z = (acc[rr][2] + bo[tx * 4 + 2]) * m;
        o.w = (acc[rr][3] + bo[tx * 4 + 3]) * m;
        *(float4*)&out[(size_t)row * 128 + tx * 4] = o;
    }
}

extern "C" void kernel_launch(void* const* d_in, const int* in_sizes, int n_in,
                              void* d_out, int out_size, void* d_ws, size_t ws_size,
                              hipStream_t stream) {
    const float* x    = (const float*)d_in[0];
    const float* dist = (const float*)d_in[1];
    const float* mask = (const float*)d_in[2];
    const float* Wq   = (const float*)d_in[3];
    const float* bq   = (const float*)d_in[4];
    const float* Wk   = (const float*)d_in[5];
    const float* bk   = (const float*)d_in[6];
    const float* Wv   = (const float*)d_in[7];
    const float* bv   = (const float*)d_in[8];
    const float* Wo   = (const float*)d_in[9];
    const float* bo   = (const float*)d_in[10];
    float* out = (float*)d_out;

    const size_t per = (size_t)B_ * H_ * N_ * D_;  // 8,388,608 elements
    unsigned short* qb = (unsigned short*)d_ws;    // bf16 (B,H,N,D)
    unsigned short* kb = qb + per;                 // bf16 (B,H,N,D)
    unsigned short* vb = kb + per;                 // bf16 (B,H,D,N)
    float* yb = (float*)(vb + per);                // fp32 (B,N,H*D)

    qkv_kernel<<<6144, 256, 0, stream>>>(x, mask, Wq, bq, Wk, bk, Wv, bv, qb, kb, vb);
    attn_kernel<<<4096, 256, 0, stream>>>(qb, kb, vb, dist, mask, yb);
    oproj_kernel<<<256, 256, 0, stream>>>(yb, Wo, bo, mask, out);
}

// Round 3
// 262.672 us; speedup vs baseline: 2.3348x; 1.5531x over previous
//
#include <hip/hip_runtime.h>
#include <hip/hip_bf16.h>

// Problem constants
#define B_ 16
#define N_ 512
#define H_ 8
#define D_ 128
#define HD_ 1024
#define SCALE_ 0.08838834764831845f  // 1/sqrt(128)

typedef __attribute__((ext_vector_type(8))) short bf16x8;  // 8 bf16 = 4 VGPR
typedef __attribute__((ext_vector_type(4))) float f32x4;   // MFMA 16x16 C/D

__device__ __forceinline__ unsigned short f2bf(float f) {
    union { __hip_bfloat16 h; unsigned short u; } cv;
    cv.h = __float2bfloat16(f);
    return cv.u;
}
__device__ __forceinline__ float bf2f(unsigned short u) {
    union { unsigned int i; float f; } cv;
    cv.i = ((unsigned int)u) << 16;
    return cv.f;
}

// ---------------------------------------------------------------------------
// Kernel 0: weight prep (one-time). Builds:
//   wTh/wTl: [3][1024 cols][128 k] bf16 hi/lo split of Wq,Wk,Wv transposed
//   woT:     [128 n][1024 k] bf16 of Wo transposed
// 32x32 LDS tile transpose; 512 blocks.
// ---------------------------------------------------------------------------
__global__ __launch_bounds__(256) void prep_kernel(
    const float* __restrict__ Wq, const float* __restrict__ Wk,
    const float* __restrict__ Wv, const float* __restrict__ Wo,
    unsigned short* __restrict__ wTh, unsigned short* __restrict__ wTl,
    unsigned short* __restrict__ woT)
{
    __shared__ float T[32][33];
    const int tile = blockIdx.x;
    const int t = threadIdx.x;
    if (tile < 384) {
        const int w = tile / 128;
        const int rem = tile % 128;
        const int kt = rem & 3;    // 128/32 k-tiles
        const int ct = rem >> 2;   // 1024/32 col-tiles
        const float* W = (w == 0) ? Wq : (w == 1) ? Wk : Wv;
        const int k0 = kt * 32, c0 = ct * 32;
        #pragma unroll
        for (int u = 0; u < 4; u++) {
            int lin = t + 256 * u; int r = lin >> 5, c = lin & 31;
            T[r][c] = W[(size_t)(k0 + r) * 1024 + c0 + c];
        }
        __syncthreads();
        unsigned short* oh = wTh + (size_t)w * 131072;
        unsigned short* ol = wTl + (size_t)w * 131072;
        #pragma unroll
        for (int u = 0; u < 4; u++) {
            int lin = t + 256 * u; int c = lin >> 5, r = lin & 31;
            float v = T[r][c];
            unsigned short hi = f2bf(v);
            float lo = v - bf2f(hi);
            oh[(size_t)(c0 + c) * 128 + k0 + r] = hi;
            ol[(size_t)(c0 + c) * 128 + k0 + r] = f2bf(lo);
        }
    } else {
        const int rem = tile - 384;
        const int nt = rem & 3;    // 128/32 n-tiles
        const int kt = rem >> 2;   // 1024/32 k-tiles
        const int k0 = kt * 32, n0 = nt * 32;
        #pragma unroll
        for (int u = 0; u < 4; u++) {
            int lin = t + 256 * u; int r = lin >> 5, c = lin & 31;
            T[r][c] = Wo[(size_t)(k0 + r) * 128 + n0 + c];
        }
        __syncthreads();
        #pragma unroll
        for (int u = 0; u < 4; u++) {
            int lin = t + 256 * u; int c = lin >> 5, r = lin & 31;
            woT[(size_t)(n0 + c) * 1024 + k0 + r] = f2bf(T[r][c]);
        }
    }
}

// ---------------------------------------------------------------------------
// Kernel 1: QKV projection via bf16 MFMA with hi/lo split-3 (fp32-grade):
// acc = ah*bh + al*bh + ah*bl. 64x64 tile, K=128, 4 waves.
// q,k out (B,H,N,D) bf16 (*mask, q *scale); v out (B,H,D,N) bf16 transposed.
// ---------------------------------------------------------------------------
__global__ __launch_bounds__(256) void qkv_kernel(
    const float* __restrict__ x, const float* __restrict__ mask,
    const unsigned short* __restrict__ wTh, const unsigned short* __restrict__ wTl,
    const float* __restrict__ bq, const float* __restrict__ bk,
    const float* __restrict__ bv,
    unsigned short* __restrict__ q, unsigned short* __restrict__ k,
    unsigned short* __restrict__ vT)
{
    const int cb = blockIdx.x % 48;
    const int by = blockIdx.x / 48;
    const int row0 = by * 64, c0 = cb * 64;
    const int which = c0 >> 10, w0 = c0 & 1023;
    const float* bi = (which == 0) ? bq : (which == 1) ? bk : bv;

    // stride 136 bf16 (68 words == 4 mod 32: conflict-minimal frag reads)
    __shared__ alignas(16) unsigned short Xh[64][136];
    __shared__ alignas(16) unsigned short Xl[64][136];
    __shared__ alignas(16) unsigned short Wh[64][136];
    __shared__ alignas(16) unsigned short Wl[64][136];
    __shared__ float biS[64];
    __shared__ float mskS[64];

    const int t = threadIdx.x;
    if (t < 64) { biS[t] = bi[w0 + t]; mskS[t] = mask[row0 + t]; }

    // stage x, split hi/lo
    #pragma unroll
    for (int u = 0; u < 8; u++) {
        int lin = t + 256 * u; int row = lin >> 5, c4 = lin & 31;
        float4 xv = *(const float4*)&x[(size_t)(row0 + row) * 128 + c4 * 4];
        ushort4 hh, ll;
        hh.x = f2bf(xv.x); ll.x = f2bf(xv.x - bf2f(hh.x));
        hh.y = f2bf(xv.y); ll.y = f2bf(xv.y - bf2f(hh.y));
        hh.z = f2bf(xv.z); ll.z = f2bf(xv.z - bf2f(hh.z));
        hh.w = f2bf(xv.w); ll.w = f2bf(xv.w - bf2f(hh.w));
        *(ushort4*)&Xh[row][c4 * 4] = hh;
        *(ushort4*)&Xl[row][c4 * 4] = ll;
    }
    // stage W^T tiles (straight copy from prep output)
    const unsigned short* whp = wTh + (size_t)which * 131072 + (size_t)w0 * 128;
    const unsigned short* wlp = wTl + (size_t)which * 131072 + (size_t)w0 * 128;
    #pragma unroll
    for (int u = 0; u < 4; u++) {
        int lin = t + 256 * u; int c = lin >> 4, k8 = (lin & 15) * 8;
        *(bf16x8*)&Wh[c][k8] = *(const bf16x8*)&whp[(size_t)c * 128 + k8];
        *(bf16x8*)&Wl[c][k8] = *(const bf16x8*)&wlp[(size_t)c * 128 + k8];
    }
    __syncthreads();

    const int wave = t >> 6, lane = t & 63, m16 = lane & 15, g4 = lane >> 4;
    const int i0 = wave * 16;
    bf16x8 ah[4], al[4];
    #pragma unroll
    for (int c = 0; c < 4; c++) {
        ah[c] = *(const bf16x8*)&Xh[i0 + m16][c * 32 + g4 * 8];
        al[c] = *(const bf16x8*)&Xl[i0 + m16][c * 32 + g4 * 8];
    }
    const f32x4 zero = {0.f, 0.f, 0.f, 0.f};
    f32x4 acc[4] = {zero, zero, zero, zero};
    #pragma unroll
    for (int nt = 0; nt < 4; nt++) {
        #pragma unroll
        for (int kc = 0; kc < 4; kc++) {
            bf16x8 bh = *(const bf16x8*)&Wh[nt * 16 + m16][kc * 32 + g4 * 8];
            bf16x8 bl = *(const bf16x8*)&Wl[nt * 16 + m16][kc * 32 + g4 * 8];
            acc[nt] = __builtin_amdgcn_mfma_f32_16x16x32_bf16(ah[kc], bh, acc[nt], 0, 0, 0);
            acc[nt] = __builtin_amdgcn_mfma_f32_16x16x32_bf16(al[kc], bh, acc[nt], 0, 0, 0);
            acc[nt] = __builtin_amdgcn_mfma_f32_16x16x32_bf16(ah[kc], bl, acc[nt], 0, 0, 0);
        }
    }
    __syncthreads();

    const int b = row0 >> 9, h = w0 >> 7, d0 = w0 & 127;
    const int iseq0 = row0 & 511;
    unsigned short* Tr = &Xh[0][0];  // reuse, stride 72 (144 B = 9*16 aligned)
    const float sc = (which == 0) ? SCALE_ : 1.0f;

    if (which == 2) {
        // v: store transposed tile -> vT (B,H,D,N)
        #pragma unroll
        for (int nt = 0; nt < 4; nt++)
            #pragma unroll
            for (int r = 0; r < 4; r++) {
                int rowl = i0 + g4 * 4 + r;
                int col = nt * 16 + m16;
                Tr[col * 72 + rowl] = f2bf((acc[nt][r] + biS[col]) * mskS[rowl]);
            }
        __syncthreads();
        unsigned short* vbase = vT + ((size_t)(b * 8 + h) * 128 + d0) * 512 + iseq0;
        #pragma unroll
        for (int u = 0; u < 2; u++) {
            int lin = t + 256 * u; int dl = lin >> 3, i8 = (lin & 7) * 8;
            *(bf16x8*)&vbase[(size_t)dl * 512 + i8] = *(const bf16x8*)&Tr[dl * 72 + i8];
        }
    } else {
        #pragma unroll
        for (int nt = 0; nt < 4; nt++)
            #pragma unroll
            for (int r = 0; r < 4; r++) {
                int rowl = i0 + g4 * 4 + r;
                int col = nt * 16 + m16;
                Tr[rowl * 72 + col] = f2bf((acc[nt][r] + biS[col]) * (mskS[rowl] * sc));
            }
        __syncthreads();
        unsigned short* dst = ((which == 0) ? q : k) +
                              ((size_t)(b * 8 + h) * 512 + iseq0) * 128 + d0;
        #pragma unroll
        for (int u = 0; u < 2; u++) {
            int lin = t + 256 * u; int rl = lin >> 3, c8 = (lin & 7) * 8;
            *(bf16x8*)&dst[(size_t)rl * 128 + c8] = *(const bf16x8*)&Tr[rl * 72 + c8];
        }
    }
}

// ---------------------------------------------------------------------------
// Kernel 2: attention via bf16 MFMA. Block = (b,h, 16 query rows).
// dist prefetched coalesced into regs, QK accs all in regs (no per-jt LDS
// serialization), conflict-free LDS strides, XCD-swizzled blockIdx, bf16 Y
// out via LDS-staged vector stores.
// ---------------------------------------------------------------------------
__global__ __launch_bounds__(256) void attn_kernel(
    const unsigned short* __restrict__ q, const unsigned short* __restrict__ k,
    const unsigned short* __restrict__ vT, const float* __restrict__ dist,
    const float* __restrict__ mask, unsigned short* __restrict__ y)
{
    // swizzle: all 32 i-tiles of one (b,h) land on one XCD (x%8 round-robin)
    const int xid = blockIdx.x;
    const int bh = (xid & 7) * 16 + ((xid >> 3) & 15);
    const int itile = xid >> 7;
    const int b = bh >> 3, h = bh & 7;
    const int i0 = itile * 16;

    const unsigned short* qb = q + (size_t)bh * 512 * 128;
    const unsigned short* kb = k + (size_t)bh * 512 * 128;
    const unsigned short* vb = vT + (size_t)bh * 128 * 512;

    __shared__ alignas(16) float Sld[16][516];   // 516 = 4 mod 32 words: 2-way max
    __shared__ alignas(16) unsigned short Pld[16][520];  // 260 words = 4 mod 32
    __shared__ float maskb[512];
    __shared__ float rsld[16];

    const int t = threadIdx.x;
    const int wave = t >> 6, lane = t & 63;
    const int m16 = lane & 15, g4 = lane >> 4;

    // coalesced dist prefetch (16 rows x 512) into regs
    float4 dreg[8];
    #pragma unroll
    for (int u = 0; u < 8; u++) {
        int lin = t + 256 * u; int row = lin >> 7, c4 = lin & 127;
        dreg[u] = *(const float4*)&dist[((size_t)b * 512 + i0 + row) * 512 + c4 * 4];
    }
    maskb[t] = mask[b * 512 + t];
    maskb[256 + t] = mask[b * 512 + 256 + t];

    // Q A-fragments (16 rows)
    bf16x8 aq[4];
    #pragma unroll
    for (int c = 0; c < 4; c++)
        aq[c] = *(const bf16x8*)(qb + (size_t)(i0 + m16) * 128 + c * 32 + g4 * 8);

    // QK^T: all 8 j-tile accumulators in regs (wave w owns j-tiles w,w+4,..)
    const f32x4 zero = {0.f, 0.f, 0.f, 0.f};
    f32x4 sacc[8];
    #pragma unroll
    for (int jt = 0; jt < 8; jt++) {
        const int j0 = (wave + 4 * jt) * 16;
        f32x4 a = zero;
        #pragma unroll
        for (int c = 0; c < 4; c++) {
            bf16x8 bk = *(const bf16x8*)(kb + (size_t)(j0 + m16) * 128 + c * 32 + g4 * 8);
            a = __builtin_amdgcn_mfma_f32_16x16x32_bf16(aq[c], bk, a, 0, 0, 0);
        }
        sacc[jt] = a;
    }

    // dist -> Sld (coalesced b128 writes)
    #pragma unroll
    for (int u = 0; u < 8; u++) {
        int lin = t + 256 * u; int row = lin >> 7, c4 = lin & 127;
        *(float4*)&Sld[row][c4 * 4] = dreg[u];
    }
    __syncthreads();

    // combine S = QK + dist, amask -> -1e9 (disjoint columns per wave)
    #pragma unroll
    for (int jt = 0; jt < 8; jt++) {
        const int j0 = (wave + 4 * jt) * 16;
        const float mj = maskb[j0 + m16];
        #pragma unroll
        for (int r = 0; r < 4; r++) {
            int row = g4 * 4 + r;
            float mi = maskb[i0 + row];
            float sv = sacc[jt][r] + Sld[row][j0 + m16];
            Sld[row][j0 + m16] = (mi * mj == 0.0f) ? -1e9f : sv;
        }
    }
    __syncthreads();

    // softmax: wave w owns rows w*4..w*4+3
    for (int rr = 0; rr < 4; rr++) {
        int r = wave * 4 + rr;
        float p[8];
        float mx = -3e38f;
        #pragma unroll
        for (int jj = 0; jj < 8; jj++) {
            float sv = Sld[r][lane + 64 * jj];
            p[jj] = sv;
            mx = fmaxf(mx, sv);
        }
        #pragma unroll
        for (int off = 32; off; off >>= 1) mx = fmaxf(mx, __shfl_xor(mx, off));
        float sum = 0.0f;
        #pragma unroll
        for (int jj = 0; jj < 8; jj++) {
            float pv = (p[jj] <= -1e8f) ? 0.0f : __expf(p[jj] - mx);
            p[jj] = pv;
            sum += pv;
        }
        #pragma unroll
        for (int off = 32; off; off >>= 1) sum += __shfl_xor(sum, off);
        #pragma unroll
        for (int jj = 0; jj < 8; jj++) Pld[r][lane + 64 * jj] = f2bf(p[jj]);
        if (lane == 0) rsld[r] = (sum > 0.0f) ? 1.0f / sum : 0.0f;
    }
    __syncthreads();

    // PV: wave w owns d columns w*32..w*32+31
    const int d0 = wave * 32;
    f32x4 acc0 = zero, acc1 = zero;
    for (int jc = 0; jc < 16; jc++) {
        const int j0 = jc * 32;
        bf16x8 ap = *(const bf16x8*)&Pld[m16][j0 + g4 * 8];
        bf16x8 bv0 = *(const bf16x8*)(vb + (size_t)(d0 + m16) * 512 + j0 + g4 * 8);
        bf16x8 bv1 = *(const bf16x8*)(vb + (size_t)(d0 + 16 + m16) * 512 + j0 + g4 * 8);
        acc0 = __builtin_amdgcn_mfma_f32_16x16x32_bf16(ap, bv0, acc0, 0, 0, 0);
        acc1 = __builtin_amdgcn_mfma_f32_16x16x32_bf16(ap, bv1, acc1, 0, 0, 0);
    }
    // epilogue via LDS (Yst aliases Sld) -> coalesced bf16 vector stores
    unsigned short* Yst = (unsigned short*)&Sld[0][0];  // stride 136
    #pragma unroll
    for (int r = 0; r < 4; r++) {
        int row = g4 * 4 + r;
        float rsv = rsld[row];
        Yst[row * 136 + d0 + m16] = f2bf(acc0[r] * rsv);
        Yst[row * 136 + d0 + 16 + m16] = f2bf(acc1[r] * rsv);
    }
    __syncthreads();
    {
        int row = t >> 4, c8 = (t & 15) * 8;
        *(bf16x8*)&y[((size_t)(b * 512) + i0 + row) * 1024 + h * 128 + c8] =
            *(const bf16x8*)&Yst[row * 136 + c8];
    }
}

// ---------------------------------------------------------------------------
// Kernel 3: output projection via bf16 MFMA. out = Ybf16 @ Wo + bo, * mask.
// 32 rows x 128 cols per block, K=1024 in chunks of 128. 256 blocks.
// ---------------------------------------------------------------------------
__global__ __launch_bounds__(256) void oproj_kernel(
    const unsigned short* __restrict__ Y, const unsigned short* __restrict__ woT,
    const float* __restrict__ bo, const float* __restrict__ mask,
    float* __restrict__ out)
{
    const int row0 = blockIdx.x * 32;
    __shared__ alignas(16) unsigned short Ys[32][136];
    __shared__ alignas(16) unsigned short Ws[128][136];
    __shared__ float boS[128];
    __shared__ float mskS[32];

    const int t = threadIdx.x;
    if (t < 128) boS[t] = bo[t];
    if (t < 32) mskS[t] = mask[row0 + t];

    const int wave = t >> 6, lane = t & 63;
    const int m16 = lane & 15, g4 = lane >> 4;
    const int mrow = (wave & 1) * 16, n0 = (wave >> 1) * 64;

    const f32x4 zero = {0.f, 0.f, 0.f, 0.f};
    f32x4 acc[4] = {zero, zero, zero, zero};

    for (int kc0 = 0; kc0 < 1024; kc0 += 128) {
        #pragma unroll
        for (int u = 0; u < 2; u++) {
            int lin = t + 256 * u; int r = lin >> 4, k8 = (lin & 15) * 8;
            *(bf16x8*)&Ys[r][k8] =
                *(const bf16x8*)&Y[(size_t)(row0 + r) * 1024 + kc0 + k8];
        }
        #pragma unroll
        for (int u = 0; u < 8; u++) {
            int lin = t + 256 * u; int n = lin >> 4, k8 = (lin & 15) * 8;
            *(bf16x8*)&Ws[n][k8] = *(const bf16x8*)&woT[(size_t)n * 1024 + kc0 + k8];
        }
        __syncthreads();
        #pragma unroll
        for (int kc = 0; kc < 4; kc++) {
            bf16x8 a = *(const bf16x8*)&Ys[mrow + m16][kc * 32 + g4 * 8];
            #pragma unroll
            for (int nt = 0; nt < 4; nt++) {
                bf16x8 bb = *(const bf16x8*)&Ws[n0 + nt * 16 + m16][kc * 32 + g4 * 8];
                acc[nt] = __builtin_amdgcn_mfma_f32_16x16x32_bf16(a, bb, acc[nt], 0, 0, 0);
            }
        }
        __syncthreads();
    }

    float* Ot = (float*)&Ws[0][0];  // stride 132 (528 B = 33*16 aligned)
    #pragma unroll
    for (int nt = 0; nt < 4; nt++)
        #pragma unroll
        for (int r = 0; r < 4; r++) {
            int rowl = mrow + g4 * 4 + r;
            int col = n0 + nt * 16 + m16;
            Ot[rowl * 132 + col] = (acc[nt][r] + boS[col]) * mskS[rowl];
        }
    __syncthreads();
    #pragma unroll
    for (int u = 0; u < 4; u++) {
        int lin = t + 256 * u; int r = lin >> 5, c4 = lin & 31;
        *(float4*)&out[(size_t)(row0 + r) * 128 + c4 * 4] =
            *(const float4*)&Ot[r * 132 + c4 * 4];
    }
}

extern "C" void kernel_launch(void* const* d_in, const int* in_sizes, int n_in,
                              void* d_out, int out_size, void* d_ws, size_t ws_size,
                              hipStream_t stream) {
    const float* x    = (const float*)d_in[0];
    const float* dist = (const float*)d_in[1];
    const float* mask = (const float*)d_in[2];
    const float* Wq   = (const float*)d_in[3];
    const float* bq   = (const float*)d_in[4];
    const float* Wk   = (const float*)d_in[5];
    const float* bk   = (const float*)d_in[6];
    const float* Wv   = (const float*)d_in[7];
    const float* bv   = (const float*)d_in[8];
    const float* Wo   = (const float*)d_in[9];
    const float* bo   = (const float*)d_in[10];
    float* out = (float*)d_out;

    const size_t per = (size_t)B_ * H_ * N_ * D_;  // 8,388,608 elements
    unsigned short* qb  = (unsigned short*)d_ws;   // bf16 (B,H,N,D)
    unsigned short* kb  = qb + per;                // bf16 (B,H,N,D)
    unsigned short* vb  = kb + per;                // bf16 (B,H,D,N)
    unsigned short* yb  = vb + per;                // bf16 (B,N,H*D)
    unsigned short* wTh = yb + per;                // [3][1024][128]
    unsigned short* wTl = wTh + 3 * 131072;
    unsigned short* woT = wTl + 3 * 131072;        // [128][1024]

    prep_kernel<<<512, 256, 0, stream>>>(Wq, Wk, Wv, Wo, wTh, wTl, woT);
    qkv_kernel<<<6144, 256, 0, stream>>>(x, mask, wTh, wTl, bq, bk, bv, qb, kb, vb);
    attn_kernel<<<4096, 256, 0, stream>>>(qb, kb, vb, dist, mask, yb);
    oproj_kernel<<<256, 256, 0, stream>>>(yb, woT, bo, mask, out);
}

// Round 4
// 257.259 us; speedup vs baseline: 2.3839x; 1.0210x over previous
//
#include <hip/hip_runtime.h>
#include <hip/hip_bf16.h>

// Problem constants
#define B_ 16
#define N_ 512
#define H_ 8
#define D_ 128
#define HD_ 1024
#define SCALE_ 0.08838834764831845f  // 1/sqrt(128)

typedef __attribute__((ext_vector_type(8))) short bf16x8;  // 8 bf16 = 4 VGPR
typedef __attribute__((ext_vector_type(4))) float f32x4;   // MFMA 16x16 C/D

__device__ __forceinline__ unsigned short f2bf(float f) {
    union { __hip_bfloat16 h; unsigned short u; } cv;
    cv.h = __float2bfloat16(f);
    return cv.u;
}
__device__ __forceinline__ float bf2f(unsigned short u) {
    union { unsigned int i; float f; } cv;
    cv.i = ((unsigned int)u) << 16;
    return cv.f;
}

// ---------------------------------------------------------------------------
// Kernel 0a: x hi/lo split (one-time): xh = bf16(x), xl = bf16(x - xh).
// ---------------------------------------------------------------------------
__global__ __launch_bounds__(256) void xsplit_kernel(
    const float* __restrict__ x, unsigned short* __restrict__ xh,
    unsigned short* __restrict__ xl)
{
    const int idx = blockIdx.x * 256 + threadIdx.x;
    float4 v = *(const float4*)&x[(size_t)idx * 4];
    ushort4 hh, ll;
    hh.x = f2bf(v.x); ll.x = f2bf(v.x - bf2f(hh.x));
    hh.y = f2bf(v.y); ll.y = f2bf(v.y - bf2f(hh.y));
    hh.z = f2bf(v.z); ll.z = f2bf(v.z - bf2f(hh.z));
    hh.w = f2bf(v.w); ll.w = f2bf(v.w - bf2f(hh.w));
    *(ushort4*)&xh[(size_t)idx * 4] = hh;
    *(ushort4*)&xl[(size_t)idx * 4] = ll;
}

// ---------------------------------------------------------------------------
// Kernel 0b: weight prep (one-time). wTh/wTl: [3][1024][128] bf16 hi/lo of
// Wq,Wk,Wv transposed; woT: [128][1024] bf16 of Wo transposed.
// ---------------------------------------------------------------------------
__global__ __launch_bounds__(256) void prep_kernel(
    const float* __restrict__ Wq, const float* __restrict__ Wk,
    const float* __restrict__ Wv, const float* __restrict__ Wo,
    unsigned short* __restrict__ wTh, unsigned short* __restrict__ wTl,
    unsigned short* __restrict__ woT)
{
    __shared__ float T[32][33];
    const int tile = blockIdx.x;
    const int t = threadIdx.x;
    if (tile < 384) {
        const int w = tile / 128;
        const int rem = tile % 128;
        const int kt = rem & 3;
        const int ct = rem >> 2;
        const float* W = (w == 0) ? Wq : (w == 1) ? Wk : Wv;
        const int k0 = kt * 32, c0 = ct * 32;
        #pragma unroll
        for (int u = 0; u < 4; u++) {
            int lin = t + 256 * u; int r = lin >> 5, c = lin & 31;
            T[r][c] = W[(size_t)(k0 + r) * 1024 + c0 + c];
        }
        __syncthreads();
        unsigned short* oh = wTh + (size_t)w * 131072;
        unsigned short* ol = wTl + (size_t)w * 131072;
        #pragma unroll
        for (int u = 0; u < 4; u++) {
            int lin = t + 256 * u; int c = lin >> 5, r = lin & 31;
            float v = T[r][c];
            unsigned short hi = f2bf(v);
            float lo = v - bf2f(hi);
            oh[(size_t)(c0 + c) * 128 + k0 + r] = hi;
            ol[(size_t)(c0 + c) * 128 + k0 + r] = f2bf(lo);
        }
    } else {
        const int rem = tile - 384;
        const int nt = rem & 3;
        const int kt = rem >> 2;
        const int k0 = kt * 32, n0 = nt * 32;
        #pragma unroll
        for (int u = 0; u < 4; u++) {
            int lin = t + 256 * u; int r = lin >> 5, c = lin & 31;
            T[r][c] = Wo[(size_t)(k0 + r) * 128 + n0 + c];
        }
        __syncthreads();
        #pragma unroll
        for (int u = 0; u < 4; u++) {
            int lin = t + 256 * u; int c = lin >> 5, r = lin & 31;
            woT[(size_t)(n0 + c) * 1024 + k0 + r] = f2bf(T[r][c]);
        }
    }
}

// ---------------------------------------------------------------------------
// Kernel 1: QKV projection via bf16 MFMA, hi/lo split-3 accumulation.
// x pre-split by xsplit_kernel; staging is pure vector copies now.
// ---------------------------------------------------------------------------
__global__ __launch_bounds__(256) void qkv_kernel(
    const unsigned short* __restrict__ xh, const unsigned short* __restrict__ xl,
    const float* __restrict__ mask,
    const unsigned short* __restrict__ wTh, const unsigned short* __restrict__ wTl,
    const float* __restrict__ bq, const float* __restrict__ bk,
    const float* __restrict__ bv,
    unsigned short* __restrict__ q, unsigned short* __restrict__ k,
    unsigned short* __restrict__ vT)
{
    const int cb = blockIdx.x % 48;
    const int by = blockIdx.x / 48;
    const int row0 = by * 64, c0 = cb * 64;
    const int which = c0 >> 10, w0 = c0 & 1023;
    const float* bi = (which == 0) ? bq : (which == 1) ? bk : bv;

    __shared__ alignas(16) unsigned short Xh[64][136];
    __shared__ alignas(16) unsigned short Xl[64][136];
    __shared__ alignas(16) unsigned short Wh[64][136];
    __shared__ alignas(16) unsigned short Wl[64][136];
    __shared__ float biS[64];
    __shared__ float mskS[64];

    const int t = threadIdx.x;
    if (t < 64) { biS[t] = bi[w0 + t]; mskS[t] = mask[row0 + t]; }

    const unsigned short* xhp = xh + (size_t)row0 * 128;
    const unsigned short* xlp = xl + (size_t)row0 * 128;
    #pragma unroll
    for (int u = 0; u < 4; u++) {
        int lin = t + 256 * u; int row = lin >> 4, k8 = (lin & 15) * 8;
        *(bf16x8*)&Xh[row][k8] = *(const bf16x8*)&xhp[(size_t)row * 128 + k8];
        *(bf16x8*)&Xl[row][k8] = *(const bf16x8*)&xlp[(size_t)row * 128 + k8];
    }
    const unsigned short* whp = wTh + (size_t)which * 131072 + (size_t)w0 * 128;
    const unsigned short* wlp = wTl + (size_t)which * 131072 + (size_t)w0 * 128;
    #pragma unroll
    for (int u = 0; u < 4; u++) {
        int lin = t + 256 * u; int c = lin >> 4, k8 = (lin & 15) * 8;
        *(bf16x8*)&Wh[c][k8] = *(const bf16x8*)&whp[(size_t)c * 128 + k8];
        *(bf16x8*)&Wl[c][k8] = *(const bf16x8*)&wlp[(size_t)c * 128 + k8];
    }
    __syncthreads();

    const int wave = t >> 6, lane = t & 63, m16 = lane & 15, g4 = lane >> 4;
    const int i0 = wave * 16;
    bf16x8 ah[4], al[4];
    #pragma unroll
    for (int c = 0; c < 4; c++) {
        ah[c] = *(const bf16x8*)&Xh[i0 + m16][c * 32 + g4 * 8];
        al[c] = *(const bf16x8*)&Xl[i0 + m16][c * 32 + g4 * 8];
    }
    const f32x4 zero = {0.f, 0.f, 0.f, 0.f};
    f32x4 acc[4] = {zero, zero, zero, zero};
    #pragma unroll
    for (int nt = 0; nt < 4; nt++) {
        #pragma unroll
        for (int kc = 0; kc < 4; kc++) {
            bf16x8 bh = *(const bf16x8*)&Wh[nt * 16 + m16][kc * 32 + g4 * 8];
            bf16x8 bl = *(const bf16x8*)&Wl[nt * 16 + m16][kc * 32 + g4 * 8];
            acc[nt] = __builtin_amdgcn_mfma_f32_16x16x32_bf16(ah[kc], bh, acc[nt], 0, 0, 0);
            acc[nt] = __builtin_amdgcn_mfma_f32_16x16x32_bf16(al[kc], bh, acc[nt], 0, 0, 0);
            acc[nt] = __builtin_amdgcn_mfma_f32_16x16x32_bf16(ah[kc], bl, acc[nt], 0, 0, 0);
        }
    }
    __syncthreads();

    const int b = row0 >> 9, h = w0 >> 7, d0 = w0 & 127;
    const int iseq0 = row0 & 511;
    unsigned short* Tr = &Xh[0][0];  // reuse, stride 72
    const float sc = (which == 0) ? SCALE_ : 1.0f;

    if (which == 2) {
        #pragma unroll
        for (int nt = 0; nt < 4; nt++)
            #pragma unroll
            for (int r = 0; r < 4; r++) {
                int rowl = i0 + g4 * 4 + r;
                int col = nt * 16 + m16;
                Tr[col * 72 + rowl] = f2bf((acc[nt][r] + biS[col]) * mskS[rowl]);
            }
        __syncthreads();
        unsigned short* vbase = vT + ((size_t)(b * 8 + h) * 128 + d0) * 512 + iseq0;
        #pragma unroll
        for (int u = 0; u < 2; u++) {
            int lin = t + 256 * u; int dl = lin >> 3, i8 = (lin & 7) * 8;
            *(bf16x8*)&vbase[(size_t)dl * 512 + i8] = *(const bf16x8*)&Tr[dl * 72 + i8];
        }
    } else {
        #pragma unroll
        for (int nt = 0; nt < 4; nt++)
            #pragma unroll
            for (int r = 0; r < 4; r++) {
                int rowl = i0 + g4 * 4 + r;
                int col = nt * 16 + m16;
                Tr[rowl * 72 + col] = f2bf((acc[nt][r] + biS[col]) * (mskS[rowl] * sc));
            }
        __syncthreads();
        unsigned short* dst = ((which == 0) ? q : k) +
                              ((size_t)(b * 8 + h) * 512 + iseq0) * 128 + d0;
        #pragma unroll
        for (int u = 0; u < 2; u++) {
            int lin = t + 256 * u; int rl = lin >> 3, c8 = (lin & 7) * 8;
            *(bf16x8*)&dst[(size_t)rl * 128 + c8] = *(const bf16x8*)&Tr[rl * 72 + c8];
        }
    }
}

// ---------------------------------------------------------------------------
// Kernel 2: attention, register-resident. Block = (b,h, 16 query rows).
// dist loaded directly in MFMA C-layout and folded into the QK accumulators;
// softmax max/sum in registers (width-16 shuffles + 256B cross-wave LDS).
// Only P (bf16) and the Y staging live in LDS -> ~24 KB/block.
// 2-stage prefetch in both MFMA loops.
// ---------------------------------------------------------------------------
__global__ __launch_bounds__(256, 4) void attn_kernel(
    const unsigned short* __restrict__ q, const unsigned short* __restrict__ k,
    const unsigned short* __restrict__ vT, const float* __restrict__ dist,
    const float* __restrict__ mask, unsigned short* __restrict__ y)
{
    // swizzle: all 32 i-tiles of one (b,h) land on one XCD (x%8 round-robin)
    const int xid = blockIdx.x;
    const int bh = (xid & 7) * 16 + ((xid >> 3) & 15);
    const int itile = xid >> 7;
    const int b = bh >> 3, h = bh & 7;
    const int i0 = itile * 16;

    const unsigned short* qb = q + (size_t)bh * 512 * 128;
    const unsigned short* kb = k + (size_t)bh * 512 * 128;
    const unsigned short* vb = vT + (size_t)bh * 128 * 512;

    __shared__ alignas(16) unsigned short Pld[16][520];  // 260 w == 4 mod 32
    __shared__ alignas(16) unsigned short Yst[16][136];
    __shared__ float maskb[512];
    __shared__ float redMx[4][16];
    __shared__ float redSm[4][16];

    const int t = threadIdx.x;
    const int wave = t >> 6, lane = t & 63;
    const int m16 = lane & 15, g4 = lane >> 4;

    maskb[t] = mask[b * 512 + t];
    maskb[256 + t] = mask[b * 512 + 256 + t];

    // Q A-fragments (16 rows, reused across all j-tiles)
    bf16x8 aq[4];
    #pragma unroll
    for (int c = 0; c < 4; c++)
        aq[c] = *(const bf16x8*)(qb + (size_t)(i0 + m16) * 128 + c * 32 + g4 * 8);

    const float* dbase = dist + ((size_t)b * 512 + i0) * 512;
    const f32x4 zero = {0.f, 0.f, 0.f, 0.f};

    // ---- QK^T with dist folded in; 2-stage prefetch of K frags + dist ----
    f32x4 sacc[8];
    bf16x8 kfA[4], kfB[4];
    float dvA[4], dvB[4];
    {
        const int j0 = wave * 16;
        #pragma unroll
        for (int c = 0; c < 4; c++)
            kfA[c] = *(const bf16x8*)(kb + (size_t)(j0 + m16) * 128 + c * 32 + g4 * 8);
        #pragma unroll
        for (int r = 0; r < 4; r++)
            dvA[r] = dbase[(size_t)(g4 * 4 + r) * 512 + j0 + m16];
    }
    #pragma unroll
    for (int jt = 0; jt < 8; jt++) {
        if (jt < 7) {
            const int j1 = (wave + 4 * (jt + 1)) * 16;
            #pragma unroll
            for (int c = 0; c < 4; c++)
                kfB[c] = *(const bf16x8*)(kb + (size_t)(j1 + m16) * 128 + c * 32 + g4 * 8);
            #pragma unroll
            for (int r = 0; r < 4; r++)
                dvB[r] = dbase[(size_t)(g4 * 4 + r) * 512 + j1 + m16];
        }
        f32x4 a = zero;
        #pragma unroll
        for (int c = 0; c < 4; c++)
            a = __builtin_amdgcn_mfma_f32_16x16x32_bf16(aq[c], kfA[c], a, 0, 0, 0);
        #pragma unroll
        for (int r = 0; r < 4; r++) a[r] += dvA[r];
        sacc[jt] = a;
        #pragma unroll
        for (int c = 0; c < 4; c++) kfA[c] = kfB[c];
        #pragma unroll
        for (int r = 0; r < 4; r++) dvA[r] = dvB[r];
    }
    __syncthreads();  // maskb ready

    // ---- mask + in-register row max ----
    float mi[4], mx[4];
    #pragma unroll
    for (int r = 0; r < 4; r++) {
        mi[r] = maskb[i0 + g4 * 4 + r];
        mx[r] = -3.0e38f;
    }
    #pragma unroll
    for (int jt = 0; jt < 8; jt++) {
        const int j0 = (wave + 4 * jt) * 16;
        const float mj = maskb[j0 + m16];
        #pragma unroll
        for (int r = 0; r < 4; r++) {
            float s = (mi[r] * mj == 0.0f) ? -1e9f : sacc[jt][r];
            sacc[jt][r] = s;
            mx[r] = fmaxf(mx[r], s);
        }
    }
    #pragma unroll
    for (int r = 0; r < 4; r++) {
        #pragma unroll
        for (int off = 1; off < 16; off <<= 1)
            mx[r] = fmaxf(mx[r], __shfl_xor(mx[r], off));
    }
    if (m16 == 0) {
        #pragma unroll
        for (int r = 0; r < 4; r++) redMx[wave][g4 * 4 + r] = mx[r];
    }
    __syncthreads();

    float mxf[4];
    #pragma unroll
    for (int r = 0; r < 4; r++) {
        int row = g4 * 4 + r;
        mxf[r] = fmaxf(fmaxf(redMx[0][row], redMx[1][row]),
                       fmaxf(redMx[2][row], redMx[3][row]));
    }

    // ---- exp, partial sums, P -> LDS bf16 ----
    float sm[4] = {0.f, 0.f, 0.f, 0.f};
    #pragma unroll
    for (int jt = 0; jt < 8; jt++) {
        const int j0 = (wave + 4 * jt) * 16;
        #pragma unroll
        for (int r = 0; r < 4; r++) {
            float p = __expf(sacc[jt][r] - mxf[r]);
            sm[r] += p;
            Pld[g4 * 4 + r][j0 + m16] = f2bf(p);
        }
    }
    #pragma unroll
    for (int r = 0; r < 4; r++) {
        #pragma unroll
        for (int off = 1; off < 16; off <<= 1)
            sm[r] += __shfl_xor(sm[r], off);
    }
    if (m16 == 0) {
        #pragma unroll
        for (int r = 0; r < 4; r++) redSm[wave][g4 * 4 + r] = sm[r];
    }
    __syncthreads();

    // ---- PV with 2-stage prefetch; wave w owns d columns w*32..w*32+31 ----
    const int d0 = wave * 32;
    f32x4 acc0 = zero, acc1 = zero;
    bf16x8 apA, bv0A, bv1A, apB, bv0B, bv1B;
    apA = *(const bf16x8*)&Pld[m16][g4 * 8];
    bv0A = *(const bf16x8*)(vb + (size_t)(d0 + m16) * 512 + g4 * 8);
    bv1A = *(const bf16x8*)(vb + (size_t)(d0 + 16 + m16) * 512 + g4 * 8);
    #pragma unroll
    for (int jc = 0; jc < 16; jc++) {
        if (jc < 15) {
            const int j1 = (jc + 1) * 32;
            apB = *(const bf16x8*)&Pld[m16][j1 + g4 * 8];
            bv0B = *(const bf16x8*)(vb + (size_t)(d0 + m16) * 512 + j1 + g4 * 8);
            bv1B = *(const bf16x8*)(vb + (size_t)(d0 + 16 + m16) * 512 + j1 + g4 * 8);
        }
        acc0 = __builtin_amdgcn_mfma_f32_16x16x32_bf16(apA, bv0A, acc0, 0, 0, 0);
        acc1 = __builtin_amdgcn_mfma_f32_16x16x32_bf16(apA, bv1A, acc1, 0, 0, 0);
        apA = apB; bv0A = bv0B; bv1A = bv1B;
    }

    // ---- epilogue: 1/sum, stage in LDS, coalesced bf16x8 store ----
    #pragma unroll
    for (int r = 0; r < 4; r++) {
        int row = g4 * 4 + r;
        float rs = 1.0f / (redSm[0][row] + redSm[1][row] +
                           redSm[2][row] + redSm[3][row]);
        Yst[row][d0 + m16] = f2bf(acc0[r] * rs);
        Yst[row][d0 + 16 + m16] = f2bf(acc1[r] * rs);
    }
    __syncthreads();
    {
        int row = t >> 4, c8 = (t & 15) * 8;
        *(bf16x8*)&y[((size_t)(b * 512) + i0 + row) * 1024 + h * 128 + c8] =
            *(const bf16x8*)&Yst[row][c8];
    }
}

// ---------------------------------------------------------------------------
// Kernel 3: output projection via bf16 MFMA. out = Ybf16 @ Wo + bo, * mask.
// ---------------------------------------------------------------------------
__global__ __launch_bounds__(256) void oproj_kernel(
    const unsigned short* __restrict__ Y, const unsigned short* __restrict__ woT,
    const float* __restrict__ bo, const float* __restrict__ mask,
    float* __restrict__ out)
{
    const int row0 = blockIdx.x * 32;
    __shared__ alignas(16) unsigned short Ys[32][136];
    __shared__ alignas(16) unsigned short Ws[128][136];
    __shared__ float boS[128];
    __shared__ float mskS[32];

    const int t = threadIdx.x;
    if (t < 128) boS[t] = bo[t];
    if (t < 32) mskS[t] = mask[row0 + t];

    const int wave = t >> 6, lane = t & 63;
    const int m16 = lane & 15, g4 = lane >> 4;
    const int mrow = (wave & 1) * 16, n0 = (wave >> 1) * 64;

    const f32x4 zero = {0.f, 0.f, 0.f, 0.f};
    f32x4 acc[4] = {zero, zero, zero, zero};

    for (int kc0 = 0; kc0 < 1024; kc0 += 128) {
        #pragma unroll
        for (int u = 0; u < 2; u++) {
            int lin = t + 256 * u; int r = lin >> 4, k8 = (lin & 15) * 8;
            *(bf16x8*)&Ys[r][k8] =
                *(const bf16x8*)&Y[(size_t)(row0 + r) * 1024 + kc0 + k8];
        }
        #pragma unroll
        for (int u = 0; u < 8; u++) {
            int lin = t + 256 * u; int n = lin >> 4, k8 = (lin & 15) * 8;
            *(bf16x8*)&Ws[n][k8] = *(const bf16x8*)&woT[(size_t)n * 1024 + kc0 + k8];
        }
        __syncthreads();
        #pragma unroll
        for (int kc = 0; kc < 4; kc++) {
            bf16x8 a = *(const bf16x8*)&Ys[mrow + m16][kc * 32 + g4 * 8];
            #pragma unroll
            for (int nt = 0; nt < 4; nt++) {
                bf16x8 bb = *(const bf16x8*)&Ws[n0 + nt * 16 + m16][kc * 32 + g4 * 8];
                acc[nt] = __builtin_amdgcn_mfma_f32_16x16x32_bf16(a, bb, acc[nt], 0, 0, 0);
            }
        }
        __syncthreads();
    }

    float* Ot = (float*)&Ws[0][0];  // stride 132
    #pragma unroll
    for (int nt = 0; nt < 4; nt++)
        #pragma unroll
        for (int r = 0; r < 4; r++) {
            int rowl = mrow + g4 * 4 + r;
            int col = n0 + nt * 16 + m16;
            Ot[rowl * 132 + col] = (acc[nt][r] + boS[col]) * mskS[rowl];
        }
    __syncthreads();
    #pragma unroll
    for (int u = 0; u < 4; u++) {
        int lin = t + 256 * u; int r = lin >> 5, c4 = lin & 31;
        *(float4*)&out[(size_t)(row0 + r) * 128 + c4 * 4] =
            *(const float4*)&Ot[r * 132 + c4 * 4];
    }
}

extern "C" void kernel_launch(void* const* d_in, const int* in_sizes, int n_in,
                              void* d_out, int out_size, void* d_ws, size_t ws_size,
                              hipStream_t stream) {
    const float* x    = (const float*)d_in[0];
    const float* dist = (const float*)d_in[1];
    const float* mask = (const float*)d_in[2];
    const float* Wq   = (const float*)d_in[3];
    const float* bq   = (const float*)d_in[4];
    const float* Wk   = (const float*)d_in[5];
    const float* bk   = (const float*)d_in[6];
    const float* Wv   = (const float*)d_in[7];
    const float* bv   = (const float*)d_in[8];
    const float* Wo   = (const float*)d_in[9];
    const float* bo   = (const float*)d_in[10];
    float* out = (float*)d_out;

    const size_t per = (size_t)B_ * H_ * N_ * D_;  // 8,388,608 elements
    unsigned short* qb  = (unsigned short*)d_ws;   // bf16 (B,H,N,D)
    unsigned short* kb  = qb + per;                // bf16 (B,H,N,D)
    unsigned short* vb  = kb + per;                // bf16 (B,H,D,N)
    unsigned short* yb  = vb + per;                // bf16 (B,N,H*D)
    unsigned short* wTh = yb + per;                // [3][1024][128]
    unsigned short* wTl = wTh + 3 * 131072;
    unsigned short* woT = wTl + 3 * 131072;        // [128][1024]
    unsigned short* xh  = woT + 131072;            // [8192][128]
    unsigned short* xl  = xh + 1048576;

    xsplit_kernel<<<1024, 256, 0, stream>>>(x, xh, xl);
    prep_kernel<<<512, 256, 0, stream>>>(Wq, Wk, Wv, Wo, wTh, wTl, woT);
    qkv_kernel<<<6144, 256, 0, stream>>>(xh, xl, mask, wTh, wTl, bq, bk, bv, qb, kb, vb);
    attn_kernel<<<4096, 256, 0, stream>>>(qb, kb, vb, dist, mask, yb);
    oproj_kernel<<<256, 256, 0, stream>>>(yb, woT, bo, mask, out);
}

// Round 5
// 190.910 us; speedup vs baseline: 3.2124x; 1.3475x over previous
//
#include <hip/hip_runtime.h>
#include <hip/hip_bf16.h>

// Problem constants
#define B_ 16
#define N_ 512
#define H_ 8
#define D_ 128
#define HD_ 1024
#define SCALE_ 0.08838834764831845f  // 1/sqrt(128)

typedef __attribute__((ext_vector_type(8))) short bf16x8;  // 8 bf16 = 4 VGPR
typedef __attribute__((ext_vector_type(4))) float f32x4;   // MFMA 16x16 C/D

__device__ __forceinline__ unsigned short f2bf(float f) {
    union { __hip_bfloat16 h; unsigned short u; } cv;
    cv.h = __float2bfloat16(f);
    return cv.u;
}
__device__ __forceinline__ float bf2f(unsigned short u) {
    union { unsigned int i; float f; } cv;
    cv.i = ((unsigned int)u) << 16;
    return cv.f;
}

// ---------------------------------------------------------------------------
// Kernel 0a: x hi/lo split (one-time): xh = bf16(x), xl = bf16(x - xh).
// ---------------------------------------------------------------------------
__global__ __launch_bounds__(256) void xsplit_kernel(
    const float* __restrict__ x, unsigned short* __restrict__ xh,
    unsigned short* __restrict__ xl)
{
    const int idx = blockIdx.x * 256 + threadIdx.x;
    float4 v = *(const float4*)&x[(size_t)idx * 4];
    ushort4 hh, ll;
    hh.x = f2bf(v.x); ll.x = f2bf(v.x - bf2f(hh.x));
    hh.y = f2bf(v.y); ll.y = f2bf(v.y - bf2f(hh.y));
    hh.z = f2bf(v.z); ll.z = f2bf(v.z - bf2f(hh.z));
    hh.w = f2bf(v.w); ll.w = f2bf(v.w - bf2f(hh.w));
    *(ushort4*)&xh[(size_t)idx * 4] = hh;
    *(ushort4*)&xl[(size_t)idx * 4] = ll;
}

// ---------------------------------------------------------------------------
// Kernel 0b: weight prep (one-time). wTh/wTl: [3][1024][128] bf16 hi/lo of
// Wq,Wk,Wv transposed; woT: [128][1024] bf16 of Wo transposed.
// ---------------------------------------------------------------------------
__global__ __launch_bounds__(256) void prep_kernel(
    const float* __restrict__ Wq, const float* __restrict__ Wk,
    const float* __restrict__ Wv, const float* __restrict__ Wo,
    unsigned short* __restrict__ wTh, unsigned short* __restrict__ wTl,
    unsigned short* __restrict__ woT)
{
    __shared__ float T[32][33];
    const int tile = blockIdx.x;
    const int t = threadIdx.x;
    if (tile < 384) {
        const int w = tile / 128;
        const int rem = tile % 128;
        const int kt = rem & 3;
        const int ct = rem >> 2;
        const float* W = (w == 0) ? Wq : (w == 1) ? Wk : Wv;
        const int k0 = kt * 32, c0 = ct * 32;
        #pragma unroll
        for (int u = 0; u < 4; u++) {
            int lin = t + 256 * u; int r = lin >> 5, c = lin & 31;
            T[r][c] = W[(size_t)(k0 + r) * 1024 + c0 + c];
        }
        __syncthreads();
        unsigned short* oh = wTh + (size_t)w * 131072;
        unsigned short* ol = wTl + (size_t)w * 131072;
        #pragma unroll
        for (int u = 0; u < 4; u++) {
            int lin = t + 256 * u; int c = lin >> 5, r = lin & 31;
            float v = T[r][c];
            unsigned short hi = f2bf(v);
            float lo = v - bf2f(hi);
            oh[(size_t)(c0 + c) * 128 + k0 + r] = hi;
            ol[(size_t)(c0 + c) * 128 + k0 + r] = f2bf(lo);
        }
    } else {
        const int rem = tile - 384;
        const int nt = rem & 3;
        const int kt = rem >> 2;
        const int k0 = kt * 32, n0 = nt * 32;
        #pragma unroll
        for (int u = 0; u < 4; u++) {
            int lin = t + 256 * u; int r = lin >> 5, c = lin & 31;
            T[r][c] = Wo[(size_t)(k0 + r) * 128 + n0 + c];
        }
        __syncthreads();
        #pragma unroll
        for (int u = 0; u < 4; u++) {
            int lin = t + 256 * u; int c = lin >> 5, r = lin & 31;
            woT[(size_t)(n0 + c) * 1024 + k0 + r] = f2bf(T[r][c]);
        }
    }
}

// ---------------------------------------------------------------------------
// Kernel 1: QKV projection via bf16 MFMA, hi/lo split-3 accumulation.
// ---------------------------------------------------------------------------
__global__ __launch_bounds__(256) void qkv_kernel(
    const unsigned short* __restrict__ xh, const unsigned short* __restrict__ xl,
    const float* __restrict__ mask,
    const unsigned short* __restrict__ wTh, const unsigned short* __restrict__ wTl,
    const float* __restrict__ bq, const float* __restrict__ bk,
    const float* __restrict__ bv,
    unsigned short* __restrict__ q, unsigned short* __restrict__ k,
    unsigned short* __restrict__ vT)
{
    const int cb = blockIdx.x % 48;
    const int by = blockIdx.x / 48;
    const int row0 = by * 64, c0 = cb * 64;
    const int which = c0 >> 10, w0 = c0 & 1023;
    const float* bi = (which == 0) ? bq : (which == 1) ? bk : bv;

    __shared__ alignas(16) unsigned short Xh[64][136];
    __shared__ alignas(16) unsigned short Xl[64][136];
    __shared__ alignas(16) unsigned short Wh[64][136];
    __shared__ alignas(16) unsigned short Wl[64][136];
    __shared__ float biS[64];
    __shared__ float mskS[64];

    const int t = threadIdx.x;
    if (t < 64) { biS[t] = bi[w0 + t]; mskS[t] = mask[row0 + t]; }

    const unsigned short* xhp = xh + (size_t)row0 * 128;
    const unsigned short* xlp = xl + (size_t)row0 * 128;
    #pragma unroll
    for (int u = 0; u < 4; u++) {
        int lin = t + 256 * u; int row = lin >> 4, k8 = (lin & 15) * 8;
        *(bf16x8*)&Xh[row][k8] = *(const bf16x8*)&xhp[(size_t)row * 128 + k8];
        *(bf16x8*)&Xl[row][k8] = *(const bf16x8*)&xlp[(size_t)row * 128 + k8];
    }
    const unsigned short* whp = wTh + (size_t)which * 131072 + (size_t)w0 * 128;
    const unsigned short* wlp = wTl + (size_t)which * 131072 + (size_t)w0 * 128;
    #pragma unroll
    for (int u = 0; u < 4; u++) {
        int lin = t + 256 * u; int c = lin >> 4, k8 = (lin & 15) * 8;
        *(bf16x8*)&Wh[c][k8] = *(const bf16x8*)&whp[(size_t)c * 128 + k8];
        *(bf16x8*)&Wl[c][k8] = *(const bf16x8*)&wlp[(size_t)c * 128 + k8];
    }
    __syncthreads();

    const int wave = t >> 6, lane = t & 63, m16 = lane & 15, g4 = lane >> 4;
    const int i0 = wave * 16;
    bf16x8 ah[4], al[4];
    #pragma unroll
    for (int c = 0; c < 4; c++) {
        ah[c] = *(const bf16x8*)&Xh[i0 + m16][c * 32 + g4 * 8];
        al[c] = *(const bf16x8*)&Xl[i0 + m16][c * 32 + g4 * 8];
    }
    const f32x4 zero = {0.f, 0.f, 0.f, 0.f};
    f32x4 acc[4] = {zero, zero, zero, zero};
    #pragma unroll
    for (int nt = 0; nt < 4; nt++) {
        #pragma unroll
        for (int kc = 0; kc < 4; kc++) {
            bf16x8 bh = *(const bf16x8*)&Wh[nt * 16 + m16][kc * 32 + g4 * 8];
            bf16x8 bl = *(const bf16x8*)&Wl[nt * 16 + m16][kc * 32 + g4 * 8];
            acc[nt] = __builtin_amdgcn_mfma_f32_16x16x32_bf16(ah[kc], bh, acc[nt], 0, 0, 0);
            acc[nt] = __builtin_amdgcn_mfma_f32_16x16x32_bf16(al[kc], bh, acc[nt], 0, 0, 0);
            acc[nt] = __builtin_amdgcn_mfma_f32_16x16x32_bf16(ah[kc], bl, acc[nt], 0, 0, 0);
        }
    }
    __syncthreads();

    const int b = row0 >> 9, h = w0 >> 7, d0 = w0 & 127;
    const int iseq0 = row0 & 511;
    unsigned short* Tr = &Xh[0][0];  // reuse, stride 72
    const float sc = (which == 0) ? SCALE_ : 1.0f;

    if (which == 2) {
        #pragma unroll
        for (int nt = 0; nt < 4; nt++)
            #pragma unroll
            for (int r = 0; r < 4; r++) {
                int rowl = i0 + g4 * 4 + r;
                int col = nt * 16 + m16;
                Tr[col * 72 + rowl] = f2bf((acc[nt][r] + biS[col]) * mskS[rowl]);
            }
        __syncthreads();
        unsigned short* vbase = vT + ((size_t)(b * 8 + h) * 128 + d0) * 512 + iseq0;
        #pragma unroll
        for (int u = 0; u < 2; u++) {
            int lin = t + 256 * u; int dl = lin >> 3, i8 = (lin & 7) * 8;
            *(bf16x8*)&vbase[(size_t)dl * 512 + i8] = *(const bf16x8*)&Tr[dl * 72 + i8];
        }
    } else {
        #pragma unroll
        for (int nt = 0; nt < 4; nt++)
            #pragma unroll
            for (int r = 0; r < 4; r++) {
                int rowl = i0 + g4 * 4 + r;
                int col = nt * 16 + m16;
                Tr[rowl * 72 + col] = f2bf((acc[nt][r] + biS[col]) * (mskS[rowl] * sc));
            }
        __syncthreads();
        unsigned short* dst = ((which == 0) ? q : k) +
                              ((size_t)(b * 8 + h) * 512 + iseq0) * 128 + d0;
        #pragma unroll
        for (int u = 0; u < 2; u++) {
            int lin = t + 256 * u; int rl = lin >> 3, c8 = (lin & 7) * 8;
            *(bf16x8*)&dst[(size_t)rl * 128 + c8] = *(const bf16x8*)&Tr[rl * 72 + c8];
        }
    }
}

// ---------------------------------------------------------------------------
// Kernel 2: flash-style attention. Block = (b,h, 64 q-rows); 4 waves, each
// owns 16 rows. Loop over 8 key-chunks of 64: K(64x128) + VT(128x64) staged
// in LDS (shared by all waves -> 8x MFMA per global byte), online softmax in
// registers, P through per-wave LDS, register-held prefetch across barriers.
// Swizzle: the 8 h-blocks sharing a dist slice land on one XCD.
// ---------------------------------------------------------------------------
__global__ __launch_bounds__(256, 2) void attn_kernel(
    const unsigned short* __restrict__ q, const unsigned short* __restrict__ k,
    const unsigned short* __restrict__ vT, const float* __restrict__ dist,
    const float* __restrict__ mask, unsigned short* __restrict__ y)
{
    const int xid = blockIdx.x;          // 1024 blocks
    const int h = xid >> 7;              // 0..7
    const int b = (xid >> 3) & 15;       // 0..15
    const int itile = xid & 7;           // 0..7 -> XCD id; h-group shares dist
    const int bh = b * 8 + h;
    const int i0 = itile * 64;

    const unsigned short* qb = q + (size_t)bh * 512 * 128;
    const unsigned short* kb = k + (size_t)bh * 512 * 128;
    const unsigned short* vb = vT + (size_t)bh * 128 * 512;

    __shared__ alignas(16) unsigned short Ks[64][136];   // K chunk, natural (j,d)
    __shared__ alignas(16) unsigned short Vs[128][72];   // V chunk, VT (d,j)
    __shared__ alignas(16) unsigned short Ps[4][16][72]; // per-wave P
    __shared__ float maskb[512];

    const int t = threadIdx.x;
    const int wave = t >> 6, lane = t & 63;
    const int m16 = lane & 15, g4 = lane >> 4;
    const int iw = i0 + wave * 16;       // wave's first q-row (seq index)

    maskb[t] = mask[b * 512 + t];
    maskb[256 + t] = mask[b * 512 + 256 + t];

    // Q A-fragments (wave's 16 rows; reused across all chunks)
    bf16x8 aq[4];
    #pragma unroll
    for (int c = 0; c < 4; c++)
        aq[c] = *(const bf16x8*)(qb + (size_t)(iw + m16) * 128 + c * 32 + g4 * 8);

    // staging index precompute
    const int krow = t >> 2, kcol = (t & 3) * 32;   // K: 4 thr/row of 128
    const int vrow = t >> 1, vcol = (t & 1) * 32;   // V: 2 thr/row of 64

    // stage chunk 0
    {
        bf16x8 kp[4], vp[4];
        #pragma unroll
        for (int u = 0; u < 4; u++) {
            kp[u] = *(const bf16x8*)(kb + (size_t)krow * 128 + kcol + u * 8);
            vp[u] = *(const bf16x8*)(vb + (size_t)vrow * 512 + vcol + u * 8);
        }
        #pragma unroll
        for (int u = 0; u < 4; u++) {
            *(bf16x8*)&Ks[krow][kcol + u * 8] = kp[u];
            *(bf16x8*)&Vs[vrow][vcol + u * 8] = vp[u];
        }
    }
    __syncthreads();

    const float* dbase = dist + ((size_t)b * 512 + iw) * 512;
    const f32x4 zero = {0.f, 0.f, 0.f, 0.f};

    float mi[4];
    #pragma unroll
    for (int r = 0; r < 4; r++) mi[r] = maskb[iw - b * 0 + g4 * 4 + r - 0 + 0 + 0];
    // (iw is already a 0..511 seq index)
    #pragma unroll
    for (int r = 0; r < 4; r++) mi[r] = maskb[iw + g4 * 4 + r];

    float rm[4] = {-3.0e38f, -3.0e38f, -3.0e38f, -3.0e38f};
    float rl[4] = {0.f, 0.f, 0.f, 0.f};
    f32x4 Ot[8] = {zero, zero, zero, zero, zero, zero, zero, zero};

    for (int c = 0; c < 8; c++) {
        const int j0 = c * 64;
        // dist for current chunk (L2-local after swizzle; hidden by QK MFMAs)
        float dpre[16];
        #pragma unroll
        for (int jt = 0; jt < 4; jt++)
            #pragma unroll
            for (int r = 0; r < 4; r++)
                dpre[jt * 4 + r] =
                    dbase[(size_t)(g4 * 4 + r) * 512 + j0 + jt * 16 + m16];
        // prefetch next chunk K/V into regs
        bf16x8 kp[4], vp[4];
        if (c < 7) {
            const int j0n = j0 + 64;
            #pragma unroll
            for (int u = 0; u < 4; u++) {
                kp[u] = *(const bf16x8*)(kb + (size_t)(j0n + krow) * 128 + kcol + u * 8);
                vp[u] = *(const bf16x8*)(vb + (size_t)vrow * 512 + j0n + vcol + u * 8);
            }
        }

        // QK^T from LDS: 16 MFMAs
        f32x4 s[4];
        #pragma unroll
        for (int jt = 0; jt < 4; jt++) {
            f32x4 a = zero;
            #pragma unroll
            for (int cc = 0; cc < 4; cc++) {
                bf16x8 bk = *(const bf16x8*)&Ks[jt * 16 + m16][cc * 32 + g4 * 8];
                a = __builtin_amdgcn_mfma_f32_16x16x32_bf16(aq[cc], bk, a, 0, 0, 0);
            }
            s[jt] = a;
        }

        // + dist, mask, chunk row-max
        float mrow[4] = {-3.0e38f, -3.0e38f, -3.0e38f, -3.0e38f};
        #pragma unroll
        for (int jt = 0; jt < 4; jt++) {
            float mj = maskb[j0 + jt * 16 + m16];
            #pragma unroll
            for (int r = 0; r < 4; r++) {
                float sv = (mi[r] * mj == 0.0f) ? -1e9f : s[jt][r] + dpre[jt * 4 + r];
                s[jt][r] = sv;
                mrow[r] = fmaxf(mrow[r], sv);
            }
        }
        #pragma unroll
        for (int r = 0; r < 4; r++) {
            #pragma unroll
            for (int off = 1; off < 16; off <<= 1)
                mrow[r] = fmaxf(mrow[r], __shfl_xor(mrow[r], off));
        }
        // online update
        float alpha[4];
        #pragma unroll
        for (int r = 0; r < 4; r++) {
            float nm = fmaxf(rm[r], mrow[r]);
            alpha[r] = __expf(rm[r] - nm);
            rm[r] = nm;
            rl[r] *= alpha[r];
        }
        #pragma unroll
        for (int nt = 0; nt < 8; nt++)
            #pragma unroll
            for (int r = 0; r < 4; r++) Ot[nt][r] *= alpha[r];
        // exp, partial sums, P -> per-wave LDS
        float psum[4] = {0.f, 0.f, 0.f, 0.f};
        #pragma unroll
        for (int jt = 0; jt < 4; jt++)
            #pragma unroll
            for (int r = 0; r < 4; r++) {
                float p = __expf(s[jt][r] - rm[r]);
                psum[r] += p;
                Ps[wave][g4 * 4 + r][jt * 16 + m16] = f2bf(p);
            }
        #pragma unroll
        for (int r = 0; r < 4; r++) {
            #pragma unroll
            for (int off = 1; off < 16; off <<= 1)
                psum[r] += __shfl_xor(psum[r], off);
            rl[r] += psum[r];
        }

        // PV from LDS: A = P frags (wave-private, same-wave ordering), 16 MFMAs
        bf16x8 pa[2];
        pa[0] = *(const bf16x8*)&Ps[wave][m16][g4 * 8];
        pa[1] = *(const bf16x8*)&Ps[wave][m16][32 + g4 * 8];
        #pragma unroll
        for (int kc = 0; kc < 2; kc++)
            #pragma unroll
            for (int nt = 0; nt < 8; nt++) {
                bf16x8 bv = *(const bf16x8*)&Vs[nt * 16 + m16][kc * 32 + g4 * 8];
                Ot[nt] = __builtin_amdgcn_mfma_f32_16x16x32_bf16(pa[kc], bv, Ot[nt], 0, 0, 0);
            }

        if (c < 7) {
            __syncthreads();
            #pragma unroll
            for (int u = 0; u < 4; u++) {
                *(bf16x8*)&Ks[krow][kcol + u * 8] = kp[u];
                *(bf16x8*)&Vs[vrow][vcol + u * 8] = vp[u];
            }
            __syncthreads();
        }
    }

    // epilogue: normalize, stage wave's 16x128 tile in (freed) Ks, store bf16
    __syncthreads();
    float rs[4];
    #pragma unroll
    for (int r = 0; r < 4; r++) rs[r] = (rl[r] > 0.f) ? 1.0f / rl[r] : 0.f;
    #pragma unroll
    for (int nt = 0; nt < 8; nt++)
        #pragma unroll
        for (int r = 0; r < 4; r++)
            Ks[wave * 16 + g4 * 4 + r][nt * 16 + m16] = f2bf(Ot[nt][r] * rs[r]);
    #pragma unroll
    for (int u = 0; u < 4; u++) {
        int lin = lane + 64 * u;           // 256 segs of 8 over 16 rows
        int row = lin >> 4, seg = lin & 15;
        *(bf16x8*)&y[((size_t)(b * 512) + iw + row) * 1024 + h * 128 + seg * 8] =
            *(const bf16x8*)&Ks[wave * 16 + row][seg * 8];
    }
}

// ---------------------------------------------------------------------------
// Kernel 3: output projection via bf16 MFMA. out = Ybf16 @ Wo + bo, * mask.
// ---------------------------------------------------------------------------
__global__ __launch_bounds__(256) void oproj_kernel(
    const unsigned short* __restrict__ Y, const unsigned short* __restrict__ woT,
    const float* __restrict__ bo, const float* __restrict__ mask,
    float* __restrict__ out)
{
    const int row0 = blockIdx.x * 32;
    __shared__ alignas(16) unsigned short Ys[32][136];
    __shared__ alignas(16) unsigned short Ws[128][136];
    __shared__ float boS[128];
    __shared__ float mskS[32];

    const int t = threadIdx.x;
    if (t < 128) boS[t] = bo[t];
    if (t < 32) mskS[t] = mask[row0 + t];

    const int wave = t >> 6, lane = t & 63;
    const int m16 = lane & 15, g4 = lane >> 4;
    const int mrow = (wave & 1) * 16, n0 = (wave >> 1) * 64;

    const f32x4 zero = {0.f, 0.f, 0.f, 0.f};
    f32x4 acc[4] = {zero, zero, zero, zero};

    for (int kc0 = 0; kc0 < 1024; kc0 += 128) {
        #pragma unroll
        for (int u = 0; u < 2; u++) {
            int lin = t + 256 * u; int r = lin >> 4, k8 = (lin & 15) * 8;
            *(bf16x8*)&Ys[r][k8] =
                *(const bf16x8*)&Y[(size_t)(row0 + r) * 1024 + kc0 + k8];
        }
        #pragma unroll
        for (int u = 0; u < 8; u++) {
            int lin = t + 256 * u; int n = lin >> 4, k8 = (lin & 15) * 8;
            *(bf16x8*)&Ws[n][k8] = *(const bf16x8*)&woT[(size_t)n * 1024 + kc0 + k8];
        }
        __syncthreads();
        #pragma unroll
        for (int kc = 0; kc < 4; kc++) {
            bf16x8 a = *(const bf16x8*)&Ys[mrow + m16][kc * 32 + g4 * 8];
            #pragma unroll
            for (int nt = 0; nt < 4; nt++) {
                bf16x8 bb = *(const bf16x8*)&Ws[n0 + nt * 16 + m16][kc * 32 + g4 * 8];
                acc[nt] = __builtin_amdgcn_mfma_f32_16x16x32_bf16(a, bb, acc[nt], 0, 0, 0);
            }
        }
        __syncthreads();
    }

    float* Ot = (float*)&Ws[0][0];  // stride 132
    #pragma unroll
    for (int nt = 0; nt < 4; nt++)
        #pragma unroll
        for (int r = 0; r < 4; r++) {
            int rowl = mrow + g4 * 4 + r;
            int col = n0 + nt * 16 + m16;
            Ot[rowl * 132 + col] = (acc[nt][r] + boS[col]) * mskS[rowl];
        }
    __syncthreads();
    #pragma unroll
    for (int u = 0; u < 4; u++) {
        int lin = t + 256 * u; int r = lin >> 5, c4 = lin & 31;
        *(float4*)&out[(size_t)(row0 + r) * 128 + c4 * 4] =
            *(const float4*)&Ot[r * 132 + c4 * 4];
    }
}

extern "C" void kernel_launch(void* const* d_in, const int* in_sizes, int n_in,
                              void* d_out, int out_size, void* d_ws, size_t ws_size,
                              hipStream_t stream) {
    const float* x    = (const float*)d_in[0];
    const float* dist = (const float*)d_in[1];
    const float* mask = (const float*)d_in[2];
    const float* Wq   = (const float*)d_in[3];
    const float* bq   = (const float*)d_in[4];
    const float* Wk   = (const float*)d_in[5];
    const float* bk   = (const float*)d_in[6];
    const float* Wv   = (const float*)d_in[7];
    const float* bv   = (const float*)d_in[8];
    const float* Wo   = (const float*)d_in[9];
    const float* bo   = (const float*)d_in[10];
    float* out = (float*)d_out;

    const size_t per = (size_t)B_ * H_ * N_ * D_;  // 8,388,608 elements
    unsigned short* qb  = (unsigned short*)d_ws;   // bf16 (B,H,N,D)
    unsigned short* kb  = qb + per;                // bf16 (B,H,N,D)
    unsigned short* vb  = kb + per;                // bf16 (B,H,D,N)
    unsigned short* yb  = vb + per;                // bf16 (B,N,H*D)
    unsigned short* wTh = yb + per;                // [3][1024][128]
    unsigned short* wTl = wTh + 3 * 131072;
    unsigned short* woT = wTl + 3 * 131072;        // [128][1024]
    unsigned short* xh  = woT + 131072;            // [8192][128]
    unsigned short* xl  = xh + 1048576;

    xsplit_kernel<<<1024, 256, 0, stream>>>(x, xh, xl);
    prep_kernel<<<512, 256, 0, stream>>>(Wq, Wk, Wv, Wo, wTh, wTl, woT);
    qkv_kernel<<<6144, 256, 0, stream>>>(xh, xl, mask, wTh, wTl, bq, bk, bv, qb, kb, vb);
    attn_kernel<<<1024, 256, 0, stream>>>(qb, kb, vb, dist, mask, yb);
    oproj_kernel<<<256, 256, 0, stream>>>(yb, woT, bo, mask, out);
}

// Round 6
// 186.375 us; speedup vs baseline: 3.2905x; 1.0243x over previous
//
#include <hip/hip_runtime.h>
#include <hip/hip_bf16.h>

// Problem constants
#define B_ 16
#define N_ 512
#define H_ 8
#define D_ 128
#define HD_ 1024
#define SCALE_ 0.08838834764831845f  // 1/sqrt(128)

typedef __attribute__((ext_vector_type(8))) short bf16x8;     // 8 bf16 = 4 VGPR
typedef __attribute__((ext_vector_type(4))) float f32x4;      // MFMA 16x16 C/D
typedef __attribute__((ext_vector_type(4))) _Float16 f16x4;   // 16x16x16 A/B

__device__ __forceinline__ unsigned short f2bf(float f) {
    union { __hip_bfloat16 h; unsigned short u; } cv;
    cv.h = __float2bfloat16(f);
    return cv.u;
}
__device__ __forceinline__ float bf2f(unsigned short u) {
    union { unsigned int i; float f; } cv;
    cv.i = ((unsigned int)u) << 16;
    return cv.f;
}
__device__ __forceinline__ unsigned short f2h(float f) {
    union { _Float16 h; unsigned short u; } cv;
    cv.h = (_Float16)f;
    return cv.u;
}

// ---------------------------------------------------------------------------
// Kernel 0a: x hi/lo split (one-time): xh = bf16(x), xl = bf16(x - xh).
// ---------------------------------------------------------------------------
__global__ __launch_bounds__(256) void xsplit_kernel(
    const float* __restrict__ x, unsigned short* __restrict__ xh,
    unsigned short* __restrict__ xl)
{
    const int idx = blockIdx.x * 256 + threadIdx.x;
    float4 v = *(const float4*)&x[(size_t)idx * 4];
    ushort4 hh, ll;
    hh.x = f2bf(v.x); ll.x = f2bf(v.x - bf2f(hh.x));
    hh.y = f2bf(v.y); ll.y = f2bf(v.y - bf2f(hh.y));
    hh.z = f2bf(v.z); ll.z = f2bf(v.z - bf2f(hh.z));
    hh.w = f2bf(v.w); ll.w = f2bf(v.w - bf2f(hh.w));
    *(ushort4*)&xh[(size_t)idx * 4] = hh;
    *(ushort4*)&xl[(size_t)idx * 4] = ll;
}

// ---------------------------------------------------------------------------
// Kernel 0b: weight prep (one-time). wTh: [3][1024][128] bf16 of Wq,Wk,Wv
// transposed (hi only); woT: [128][1024] bf16 of Wo transposed.
// ---------------------------------------------------------------------------
__global__ __launch_bounds__(256) void prep_kernel(
    const float* __restrict__ Wq, const float* __restrict__ Wk,
    const float* __restrict__ Wv, const float* __restrict__ Wo,
    unsigned short* __restrict__ wTh, unsigned short* __restrict__ woT)
{
    __shared__ float T[32][33];
    const int tile = blockIdx.x;
    const int t = threadIdx.x;
    if (tile < 384) {
        const int w = tile / 128;
        const int rem = tile % 128;
        const int kt = rem & 3;
        const int ct = rem >> 2;
        const float* W = (w == 0) ? Wq : (w == 1) ? Wk : Wv;
        const int k0 = kt * 32, c0 = ct * 32;
        #pragma unroll
        for (int u = 0; u < 4; u++) {
            int lin = t + 256 * u; int r = lin >> 5, c = lin & 31;
            T[r][c] = W[(size_t)(k0 + r) * 1024 + c0 + c];
        }
        __syncthreads();
        unsigned short* oh = wTh + (size_t)w * 131072;
        #pragma unroll
        for (int u = 0; u < 4; u++) {
            int lin = t + 256 * u; int c = lin >> 5, r = lin & 31;
            oh[(size_t)(c0 + c) * 128 + k0 + r] = f2bf(T[r][c]);
        }
    } else {
        const int rem = tile - 384;
        const int nt = rem & 3;
        const int kt = rem >> 2;
        const int k0 = kt * 32, n0 = nt * 32;
        #pragma unroll
        for (int u = 0; u < 4; u++) {
            int lin = t + 256 * u; int r = lin >> 5, c = lin & 31;
            T[r][c] = Wo[(size_t)(k0 + r) * 128 + n0 + c];
        }
        __syncthreads();
        #pragma unroll
        for (int u = 0; u < 4; u++) {
            int lin = t + 256 * u; int c = lin >> 5, r = lin & 31;
            woT[(size_t)(n0 + c) * 1024 + k0 + r] = f2bf(T[r][c]);
        }
    }
}

// ---------------------------------------------------------------------------
// Kernel 1: QKV projection. 64 rows x 128 cols (one full head dim) per
// block, 2-pass hi/lo: acc = xh*Wh + xl*Wh. q,k bf16 (B,H,N,D); v f16
// TRANSPOSED (B,H,D,N).
// ---------------------------------------------------------------------------
__global__ __launch_bounds__(256, 2) void qkv_kernel(
    const unsigned short* __restrict__ xh, const unsigned short* __restrict__ xl,
    const float* __restrict__ mask, const unsigned short* __restrict__ wTh,
    const float* __restrict__ bq, const float* __restrict__ bk,
    const float* __restrict__ bv,
    unsigned short* __restrict__ q, unsigned short* __restrict__ k,
    unsigned short* __restrict__ vT)
{
    const int cb = blockIdx.x % 24;    // 128-wide col tile in [0,3072)
    const int by = blockIdx.x / 24;    // 64-tall row tile
    const int row0 = by * 64, c0 = cb * 128;
    const int which = c0 >> 10, w0 = c0 & 1023;
    const float* bi = (which == 0) ? bq : (which == 1) ? bk : bv;

    __shared__ alignas(16) unsigned short Xh[64][136];
    __shared__ alignas(16) unsigned short Xl[64][136];
    __shared__ alignas(16) unsigned short Wh[128][136];
    __shared__ float biS[128];
    __shared__ float mskS[64];

    const int t = threadIdx.x;
    if (t < 128) biS[t] = bi[w0 + t];
    if (t < 64) mskS[t] = mask[row0 + t];

    const unsigned short* xhp = xh + (size_t)row0 * 128;
    const unsigned short* xlp = xl + (size_t)row0 * 128;
    #pragma unroll
    for (int u = 0; u < 4; u++) {
        int lin = t + 256 * u; int row = lin >> 4, k8 = (lin & 15) * 8;
        *(bf16x8*)&Xh[row][k8] = *(const bf16x8*)&xhp[(size_t)row * 128 + k8];
        *(bf16x8*)&Xl[row][k8] = *(const bf16x8*)&xlp[(size_t)row * 128 + k8];
    }
    const unsigned short* whp = wTh + (size_t)which * 131072 + (size_t)w0 * 128;
    #pragma unroll
    for (int u = 0; u < 8; u++) {
        int lin = t + 256 * u; int c = lin >> 4, k8 = (lin & 15) * 8;
        *(bf16x8*)&Wh[c][k8] = *(const bf16x8*)&whp[(size_t)c * 128 + k8];
    }
    __syncthreads();

    const int wave = t >> 6, lane = t & 63, m16 = lane & 15, g4 = lane >> 4;
    const int i0 = wave * 16;
    bf16x8 ah[4], al[4];
    #pragma unroll
    for (int c = 0; c < 4; c++) {
        ah[c] = *(const bf16x8*)&Xh[i0 + m16][c * 32 + g4 * 8];
        al[c] = *(const bf16x8*)&Xl[i0 + m16][c * 32 + g4 * 8];
    }
    const f32x4 zero = {0.f, 0.f, 0.f, 0.f};
    f32x4 acc[8] = {zero, zero, zero, zero, zero, zero, zero, zero};
    #pragma unroll
    for (int nt = 0; nt < 8; nt++) {
        #pragma unroll
        for (int kc = 0; kc < 4; kc++) {
            bf16x8 bh = *(const bf16x8*)&Wh[nt * 16 + m16][kc * 32 + g4 * 8];
            acc[nt] = __builtin_amdgcn_mfma_f32_16x16x32_bf16(ah[kc], bh, acc[nt], 0, 0, 0);
            acc[nt] = __builtin_amdgcn_mfma_f32_16x16x32_bf16(al[kc], bh, acc[nt], 0, 0, 0);
        }
    }
    __syncthreads();

    const int b = row0 >> 9, h = w0 >> 7;
    const int iseq0 = row0 & 511;

    if (which == 2) {
        // v: transpose-stage as f16 in (freed) Wh, write vT (B,H,D,N)
        unsigned short* Tr = &Wh[0][0];  // 128 x 72
        #pragma unroll
        for (int nt = 0; nt < 8; nt++)
            #pragma unroll
            for (int r = 0; r < 4; r++) {
                int rowl = i0 + g4 * 4 + r;
                int col = nt * 16 + m16;
                Tr[col * 72 + rowl] = f2h((acc[nt][r] + biS[col]) * mskS[rowl]);
            }
        __syncthreads();
        unsigned short* vbase = vT + (size_t)(b * 8 + h) * 128 * 512 + iseq0;
        #pragma unroll
        for (int u = 0; u < 4; u++) {
            int lin = t + 256 * u; int dl = lin >> 3, i8 = (lin & 7) * 8;
            *(bf16x8*)&vbase[(size_t)dl * 512 + i8] = *(const bf16x8*)&Tr[dl * 72 + i8];
        }
    } else {
        unsigned short* Tr = &Wh[0][0];  // 64 x 136
        const float sc = (which == 0) ? SCALE_ : 1.0f;
        #pragma unroll
        for (int nt = 0; nt < 8; nt++)
            #pragma unroll
            for (int r = 0; r < 4; r++) {
                int rowl = i0 + g4 * 4 + r;
                int col = nt * 16 + m16;
                Tr[rowl * 136 + col] = f2bf((acc[nt][r] + biS[col]) * (mskS[rowl] * sc));
            }
        __syncthreads();
        unsigned short* dst = ((which == 0) ? q : k) +
                              ((size_t)(b * 8 + h) * 512 + iseq0) * 128;
        #pragma unroll
        for (int u = 0; u < 4; u++) {
            int lin = t + 256 * u; int rl = lin >> 4, c8 = (lin & 15) * 8;
            *(bf16x8*)&dst[(size_t)rl * 128 + c8] = *(const bf16x8*)&Tr[rl * 136 + c8];
        }
    }
}

// ---------------------------------------------------------------------------
// Kernel 2: flash attention, S^T trick. Block = (b,h, 64 q-rows); 4 waves.
// QK^T computed transposed (A=K, B=Q) so each lane holds S[i=m16][j=g4*4+r]:
// softmax state is scalar/lane (2-shuffle reductions), dist/mask are float4,
// and the 4 P values are EXACTLY the A-fragment of mfma_f32_16x16x16_f16 ->
// PV straight from registers, no P LDS round-trip. V is f16 (d,j) in LDS.
// ---------------------------------------------------------------------------
__global__ __launch_bounds__(256, 2) void attn_kernel(
    const unsigned short* __restrict__ q, const unsigned short* __restrict__ k,
    const unsigned short* __restrict__ vT, const float* __restrict__ dist,
    const float* __restrict__ mask, unsigned short* __restrict__ y)
{
    const int xid = blockIdx.x;          // 1024 blocks
    const int h = xid >> 7;
    const int b = (xid >> 3) & 15;
    const int itile = xid & 7;           // XCD id; h-group shares dist in L2
    const int bh = b * 8 + h;
    const int i0 = itile * 64;

    const unsigned short* qb = q + (size_t)bh * 512 * 128;
    const unsigned short* kb = k + (size_t)bh * 512 * 128;
    const unsigned short* vb = vT + (size_t)bh * 128 * 512;  // f16 (d, j)

    __shared__ alignas(16) unsigned short Ks[64][136];
    __shared__ alignas(16) unsigned short Vs[128][72];
    __shared__ float maskb[512];

    const int t = threadIdx.x;
    const int wave = t >> 6, lane = t & 63;
    const int m16 = lane & 15, g4 = lane >> 4;
    const int iw = i0 + wave * 16;

    maskb[t] = mask[b * 512 + t];
    maskb[256 + t] = mask[b * 512 + 256 + t];

    // Q fragments: serve as MFMA B-operand (n=i=m16, k=d=g4*8..)
    bf16x8 aq[4];
    #pragma unroll
    for (int c = 0; c < 4; c++)
        aq[c] = *(const bf16x8*)(qb + (size_t)(iw + m16) * 128 + c * 32 + g4 * 8);

    const int krow = t >> 2, kcol = (t & 3) * 32;
    const int vrow = t >> 1, vcol = (t & 1) * 32;

    // stage chunk 0
    {
        bf16x8 kp[4], vp[4];
        #pragma unroll
        for (int u = 0; u < 4; u++) {
            kp[u] = *(const bf16x8*)(kb + (size_t)krow * 128 + kcol + u * 8);
            vp[u] = *(const bf16x8*)(vb + (size_t)vrow * 512 + vcol + u * 8);
        }
        #pragma unroll
        for (int u = 0; u < 4; u++) {
            *(bf16x8*)&Ks[krow][kcol + u * 8] = kp[u];
            *(bf16x8*)&Vs[vrow][vcol + u * 8] = vp[u];
        }
    }
    __syncthreads();

    const float* dbase = dist + ((size_t)b * 512 + iw) * 512;
    const float mi = maskb[iw + m16];    // this lane's query row mask
    const f32x4 zero = {0.f, 0.f, 0.f, 0.f};

    float rm = -3.0e38f, rl = 0.f;       // per-lane (query row m16)
    f32x4 Ot[8] = {zero, zero, zero, zero, zero, zero, zero, zero};

    for (int c = 0; c < 8; c++) {
        const int j0 = c * 64;
        // dist: one float4 per jt (4 consecutive j for this lane's row)
        float4 dv[4];
        #pragma unroll
        for (int jt = 0; jt < 4; jt++)
            dv[jt] = *(const float4*)&dbase[(size_t)m16 * 512 + j0 + jt * 16 + g4 * 4];
        // prefetch next chunk into regs
        bf16x8 kp[4], vp[4];
        if (c < 7) {
            const int j0n = j0 + 64;
            #pragma unroll
            for (int u = 0; u < 4; u++) {
                kp[u] = *(const bf16x8*)(kb + (size_t)(j0n + krow) * 128 + kcol + u * 8);
                vp[u] = *(const bf16x8*)(vb + (size_t)vrow * 512 + j0n + vcol + u * 8);
            }
        }

        // S^T = K·Q^T: lane gets S[i=m16][j = j0 + jt*16 + g4*4 + r]
        f32x4 s[4];
        #pragma unroll
        for (int jt = 0; jt < 4; jt++) {
            f32x4 a = zero;
            #pragma unroll
            for (int cc = 0; cc < 4; cc++) {
                bf16x8 kf = *(const bf16x8*)&Ks[jt * 16 + m16][cc * 32 + g4 * 8];
                a = __builtin_amdgcn_mfma_f32_16x16x32_bf16(kf, aq[cc], a, 0, 0, 0);
            }
            s[jt] = a;
        }

        // + dist, mask, chunk max (per-lane over 16 vals, then 2 shuffles)
        float cm = -3.0e38f;
        #pragma unroll
        for (int jt = 0; jt < 4; jt++) {
            float4 mj4 = *(const float4*)&maskb[j0 + jt * 16 + g4 * 4];
            #pragma unroll
            for (int r = 0; r < 4; r++) {
                float mj = (r == 0) ? mj4.x : (r == 1) ? mj4.y : (r == 2) ? mj4.z : mj4.w;
                float sv = (mi * mj == 0.0f) ? -1e9f : s[jt][r] + dv[jt][r];
                s[jt][r] = sv;
                cm = fmaxf(cm, sv);
            }
        }
        cm = fmaxf(cm, __shfl_xor(cm, 16));
        cm = fmaxf(cm, __shfl_xor(cm, 32));

        // online update
        float nm = fmaxf(rm, cm);
        float alpha = __expf(rm - nm);
        rm = nm;
        rl *= alpha;

        // P in f16 regs = PV A-fragments (k = g4*4 + r exactly)
        f16x4 pa[4];
        float ps = 0.f;
        #pragma unroll
        for (int jt = 0; jt < 4; jt++)
            #pragma unroll
            for (int r = 0; r < 4; r++) {
                float p = __expf(s[jt][r] - rm);
                ps += p;
                pa[jt][r] = (_Float16)p;
            }
        ps += __shfl_xor(ps, 16);
        ps += __shfl_xor(ps, 32);
        rl += ps;

        // rescale Ot (rows g4*4+r) by alpha of those rows
        float a4[4];
        #pragma unroll
        for (int r = 0; r < 4; r++) a4[r] = __shfl(alpha, g4 * 4 + r);
        #pragma unroll
        for (int dt = 0; dt < 8; dt++)
            #pragma unroll
            for (int r = 0; r < 4; r++) Ot[dt][r] *= a4[r];

        // PV: 4 jt x 8 d-tiles, B-frag = b64 from Vs
        #pragma unroll
        for (int jt = 0; jt < 4; jt++)
            #pragma unroll
            for (int dt = 0; dt < 8; dt++) {
                f16x4 vf = *(const f16x4*)&Vs[dt * 16 + m16][jt * 16 + g4 * 4];
                Ot[dt] = __builtin_amdgcn_mfma_f32_16x16x16f16(pa[jt], vf, Ot[dt], 0, 0, 0);
            }

        if (c < 7) {
            __syncthreads();
            #pragma unroll
            for (int u = 0; u < 4; u++) {
                *(bf16x8*)&Ks[krow][kcol + u * 8] = kp[u];
                *(bf16x8*)&Vs[vrow][vcol + u * 8] = vp[u];
            }
            __syncthreads();
        }
    }

    // epilogue: normalize (1/l of rows g4*4+r via shuffle), stage, store
    __syncthreads();
    float rs = (rl > 0.f) ? 1.0f / rl : 0.f;
    float rs4[4];
    #pragma unroll
    for (int r = 0; r < 4; r++) rs4[r] = __shfl(rs, g4 * 4 + r);
    #pragma unroll
    for (int dt = 0; dt < 8; dt++)
        #pragma unroll
        for (int r = 0; r < 4; r++)
            Ks[wave * 16 + g4 * 4 + r][dt * 16 + m16] = f2bf(Ot[dt][r] * rs4[r]);
    #pragma unroll
    for (int u = 0; u < 4; u++) {
        int lin = lane + 64 * u;
        int row = lin >> 4, seg = lin & 15;
        *(bf16x8*)&y[((size_t)(b * 512) + iw + row) * 1024 + h * 128 + seg * 8] =
            *(const bf16x8*)&Ks[wave * 16 + row][seg * 8];
    }
}

// ---------------------------------------------------------------------------
// Kernel 3: output projection via bf16 MFMA. out = Ybf16 @ Wo + bo, * mask.
// ---------------------------------------------------------------------------
__global__ __launch_bounds__(256) void oproj_kernel(
    const unsigned short* __restrict__ Y, const unsigned short* __restrict__ woT,
    const float* __restrict__ bo, const float* __restrict__ mask,
    float* __restrict__ out)
{
    const int row0 = blockIdx.x * 32;
    __shared__ alignas(16) unsigned short Ys[32][136];
    __shared__ alignas(16) unsigned short Ws[128][136];
    __shared__ float boS[128];
    __shared__ float mskS[32];

    const int t = threadIdx.x;
    if (t < 128) boS[t] = bo[t];
    if (t < 32) mskS[t] = mask[row0 + t];

    const int wave = t >> 6, lane = t & 63;
    const int m16 = lane & 15, g4 = lane >> 4;
    const int mrow = (wave & 1) * 16, n0 = (wave >> 1) * 64;

    const f32x4 zero = {0.f, 0.f, 0.f, 0.f};
    f32x4 acc[4] = {zero, zero, zero, zero};

    for (int kc0 = 0; kc0 < 1024; kc0 += 128) {
        #pragma unroll
        for (int u = 0; u < 2; u++) {
            int lin = t + 256 * u; int r = lin >> 4, k8 = (lin & 15) * 8;
            *(bf16x8*)&Ys[r][k8] =
                *(const bf16x8*)&Y[(size_t)(row0 + r) * 1024 + kc0 + k8];
        }
        #pragma unroll
        for (int u = 0; u < 8; u++) {
            int lin = t + 256 * u; int n = lin >> 4, k8 = (lin & 15) * 8;
            *(bf16x8*)&Ws[n][k8] = *(const bf16x8*)&woT[(size_t)n * 1024 + kc0 + k8];
        }
        __syncthreads();
        #pragma unroll
        for (int kc = 0; kc < 4; kc++) {
            bf16x8 a = *(const bf16x8*)&Ys[mrow + m16][kc * 32 + g4 * 8];
            #pragma unroll
            for (int nt = 0; nt < 4; nt++) {
                bf16x8 bb = *(const bf16x8*)&Ws[n0 + nt * 16 + m16][kc * 32 + g4 * 8];
                acc[nt] = __builtin_amdgcn_mfma_f32_16x16x32_bf16(a, bb, acc[nt], 0, 0, 0);
            }
        }
        __syncthreads();
    }

    float* Ot = (float*)&Ws[0][0];  // stride 132
    #pragma unroll
    for (int nt = 0; nt < 4; nt++)
        #pragma unroll
        for (int r = 0; r < 4; r++) {
            int rowl = mrow + g4 * 4 + r;
            int col = n0 + nt * 16 + m16;
            Ot[rowl * 132 + col] = (acc[nt][r] + boS[col]) * mskS[rowl];
        }
    __syncthreads();
    #pragma unroll
    for (int u = 0; u < 4; u++) {
        int lin = t + 256 * u; int r = lin >> 5, c4 = lin & 31;
        *(float4*)&out[(size_t)(row0 + r) * 128 + c4 * 4] =
            *(const float4*)&Ot[r * 132 + c4 * 4];
    }
}

extern "C" void kernel_launch(void* const* d_in, const int* in_sizes, int n_in,
                              void* d_out, int out_size, void* d_ws, size_t ws_size,
                              hipStream_t stream) {
    const float* x    = (const float*)d_in[0];
    const float* dist = (const float*)d_in[1];
    const float* mask = (const float*)d_in[2];
    const float* Wq   = (const float*)d_in[3];
    const float* bq   = (const float*)d_in[4];
    const float* Wk   = (const float*)d_in[5];
    const float* bk   = (const float*)d_in[6];
    const float* Wv   = (const float*)d_in[7];
    const float* bv   = (const float*)d_in[8];
    const float* Wo   = (const float*)d_in[9];
    const float* bo   = (const float*)d_in[10];
    float* out = (float*)d_out;

    const size_t per = (size_t)B_ * H_ * N_ * D_;  // 8,388,608 elements
    unsigned short* qb  = (unsigned short*)d_ws;   // bf16 (B,H,N,D)
    unsigned short* kb  = qb + per;                // bf16 (B,H,N,D)
    unsigned short* vb  = kb + per;                // f16  (B,H,D,N)
    unsigned short* yb  = vb + per;                // bf16 (B,N,H*D)
    unsigned short* wTh = yb + per;                // [3][1024][128]
    unsigned short* woT = wTh + 3 * 131072;        // [128][1024]
    unsigned short* xh  = woT + 131072;            // [8192][128]
    unsigned short* xl  = xh + 1048576;

    xsplit_kernel<<<1024, 256, 0, stream>>>(x, xh, xl);
    prep_kernel<<<512, 256, 0, stream>>>(Wq, Wk, Wv, Wo, wTh, woT);
    qkv_kernel<<<3072, 256, 0, stream>>>(xh, xl, mask, wTh, bq, bk, bv, qb, kb, vb);
    attn_kernel<<<1024, 256, 0, stream>>>(qb, kb, vb, dist, mask, yb);
    oproj_kernel<<<256, 256, 0, stream>>>(yb, woT, bo, mask, out);
}